// Round 1
// baseline (562.875 us; speedup 1.0000x reference)
//
#include <hip/hip_runtime.h>
#include <math.h>

#define FDIM 128

// ---------------- new_w0 = relu(w0 @ E_meta + b0), [128,128] -----------------
__global__ void k_new_w0(const float* __restrict__ w0, const float* __restrict__ Em,
                         const float* __restrict__ b0, float* __restrict__ out) {
    int i = blockIdx.x, j = threadIdx.x;
    float v = w0[i] * Em[j] + b0[i * FDIM + j];
    out[i * FDIM + j] = v > 0.f ? v : 0.f;
}

// ---------------- zero int buffer -----------------
__global__ void k_zero(int* __restrict__ p, int n) {
    int i = blockIdx.x * 256 + threadIdx.x;
    if (i < n) p[i] = 0;
}

// ---------------- per-dst degree count -----------------
__global__ void k_count(const int* __restrict__ ei, int* __restrict__ counts, int E) {
    int e = blockIdx.x * 256 + threadIdx.x;
    if (e < E) atomicAdd(&counts[ei[E + e]], 1);
}

// ---------------- single-block exclusive scan; also dis = rsqrt(deg+1), reset cursor ----
__global__ void k_scan(int* __restrict__ counts, int* __restrict__ rowptr,
                       float* __restrict__ dis, int n) {
    __shared__ int sm[1024];
    __shared__ int carry;
    int tid = threadIdx.x;
    if (tid == 0) carry = 0;
    __syncthreads();
    for (int base = 0; base < n; base += 1024) {
        int i = base + tid;
        int v = (i < n) ? counts[i] : 0;
        sm[tid] = v;
        __syncthreads();
        for (int off = 1; off < 1024; off <<= 1) {
            int t = (tid >= off) ? sm[tid - off] : 0;
            __syncthreads();
            sm[tid] += t;
            __syncthreads();
        }
        int incl = sm[tid];
        int excl = incl - v;
        int c0 = carry;
        if (i < n) {
            rowptr[i] = c0 + excl;
            dis[i] = rsqrtf((float)(v + 1));
            counts[i] = 0;  // becomes the scatter cursor
        }
        __syncthreads();
        if (tid == 1023) carry = c0 + incl;
        __syncthreads();
    }
    if (tid == 0) rowptr[n] = carry;
}

// ---------------- scatter edges into CSR (by dst) -----------------
__global__ void k_scatter(const int* __restrict__ ei, const int* __restrict__ rowptr,
                          int* __restrict__ cursor, const float* __restrict__ dis,
                          int* __restrict__ csr_src, float* __restrict__ csr_w, int E) {
    int e = blockIdx.x * 256 + threadIdx.x;
    if (e >= E) return;
    int s = ei[e], d = ei[E + e];
    int pos = atomicAdd(&cursor[d], 1);
    int j = rowptr[d] + pos;
    csr_src[j] = s;
    csr_w[j] = dis[s] * dis[d];
}

// ---------------- fp32 GEMM: C[n,128] = A[n,128] @ W[128,128] (+ bias) ----------------
#define BM 64
#define BK 32
__global__ __launch_bounds__(256) void k_gemm(const float* __restrict__ A,
                                              const float* __restrict__ W,
                                              const float* __restrict__ bias,
                                              float* __restrict__ C, int n) {
    __shared__ float As[BM][BK];      // 8 KB
    __shared__ float Ws[BK][FDIM];    // 16 KB
    int tid = threadIdx.x;
    int row0 = blockIdx.x * BM;
    int tx = tid & 31;   // col group: cols tx*4 .. tx*4+3
    int ty = tid >> 5;   // row group: rows ty*8 .. ty*8+7
    float acc[8][4] = {};
    for (int k0 = 0; k0 < FDIM; k0 += BK) {
        // As: 64x32 = 512 float4, 2 per thread
        for (int t = tid; t < BM * BK / 4; t += 256) {
            int r = t >> 3;          // BK/4 = 8 float4 per row
            int c4 = t & 7;
            int row = row0 + r;
            float4 v = make_float4(0.f, 0.f, 0.f, 0.f);
            if (row < n) v = *(const float4*)&A[row * FDIM + k0 + c4 * 4];
            *(float4*)&As[r][c4 * 4] = v;
        }
        // Ws: 32x128 = 1024 float4, 4 per thread
        for (int t = tid; t < BK * FDIM / 4; t += 256) {
            int r = t >> 5;          // 32 float4 per row
            int c4 = t & 31;
            *(float4*)&Ws[r][c4 * 4] = *(const float4*)&W[(k0 + r) * FDIM + c4 * 4];
        }
        __syncthreads();
#pragma unroll
        for (int k = 0; k < BK; k++) {
            float4 w = *(float4*)&Ws[k][tx * 4];
#pragma unroll
            for (int r = 0; r < 8; r++) {
                float a = As[ty * 8 + r][k];
                acc[r][0] += a * w.x;
                acc[r][1] += a * w.y;
                acc[r][2] += a * w.z;
                acc[r][3] += a * w.w;
            }
        }
        __syncthreads();
    }
    float4 b = make_float4(0.f, 0.f, 0.f, 0.f);
    if (bias) b = *(const float4*)&bias[tx * 4];
    for (int r = 0; r < 8; r++) {
        int row = row0 + ty * 8 + r;
        if (row < n) {
            float4 v;
            v.x = acc[r][0] + b.x;
            v.y = acc[r][1] + b.y;
            v.z = acc[r][2] + b.z;
            v.w = acc[r][3] + b.w;
            *(float4*)&C[row * FDIM + tx * 4] = v;
        }
    }
}

// ---------------- aggregate: h[n] = relu(sum_{e: dst=n} hw[src]*w  + hw[n]*dis[n]^2) ----
__global__ __launch_bounds__(256) void k_aggregate(const float* __restrict__ hw,
                                                   const int* __restrict__ rowptr,
                                                   const int* __restrict__ csr_src,
                                                   const float* __restrict__ csr_w,
                                                   const float* __restrict__ dis,
                                                   float* __restrict__ h, int n) {
    int node = blockIdx.x * blockDim.y + threadIdx.y;
    if (node >= n) return;
    int f4 = threadIdx.x;  // 0..31: float4 feature group
    float d = dis[node];
    float sn = d * d;
    const float4* hwv = (const float4*)hw;
    float4 self = hwv[node * 32 + f4];
    float4 acc;
    acc.x = self.x * sn; acc.y = self.y * sn; acc.z = self.z * sn; acc.w = self.w * sn;
    int beg = rowptr[node], end = rowptr[node + 1];
    for (int j = beg; j < end; j++) {
        int s = csr_src[j];
        float w = csr_w[j];
        float4 v = hwv[s * 32 + f4];
        acc.x += v.x * w; acc.y += v.y * w; acc.z += v.z * w; acc.w += v.w * w;
    }
    float4 o;
    o.x = fmaxf(acc.x, 0.f); o.y = fmaxf(acc.y, 0.f);
    o.z = fmaxf(acc.z, 0.f); o.w = fmaxf(acc.w, 0.f);
    ((float4*)h)[node * 32 + f4] = o;
}

// ---------------- final: logits = h @ lt1_W + b; out = log_softmax(logits) ----------------
__global__ __launch_bounds__(256) void k_final(const float* __restrict__ h,
                                               const float* __restrict__ W,
                                               const float* __restrict__ bias,
                                               float* __restrict__ out, int n, int C) {
    __shared__ float Ws[FDIM * 40];
    __shared__ float hs[4][FDIM];
    int tid = threadIdx.x;
    for (int t = tid; t < FDIM * C; t += 256) Ws[t] = W[t];
    __syncthreads();
    int wave = tid >> 6, lane = tid & 63;
    int c = (lane < C) ? lane : 0;
    float b = bias[c];
    int gw = blockIdx.x * 4 + wave;
    int nw = gridDim.x * 4;
    for (int node = gw; node < n; node += nw) {
        hs[wave][lane] = h[node * FDIM + lane];
        hs[wave][lane + 64] = h[node * FDIM + 64 + lane];
        float acc = 0.f;
#pragma unroll 8
        for (int k = 0; k < FDIM; k++) acc += hs[wave][k] * Ws[k * C + c];
        float logit = acc + b;
        float v = (lane < C) ? logit : -1e30f;
        float m = v;
        for (int off = 32; off; off >>= 1) m = fmaxf(m, __shfl_xor(m, off));
        float e = (lane < C) ? __expf(logit - m) : 0.f;
        float s = e;
        for (int off = 32; off; off >>= 1) s += __shfl_xor(s, off);
        if (lane < C) out[node * C + lane] = logit - m - __logf(s);
    }
}

extern "C" void kernel_launch(void* const* d_in, const int* in_sizes, int n_in,
                              void* d_out, int out_size, void* d_ws, size_t ws_size,
                              hipStream_t stream) {
    const float* x      = (const float*)d_in[0];
    const int*   ei     = (const int*)d_in[1];
    const float* E_meta = (const float*)d_in[2];
    const float* w0     = (const float*)d_in[3];
    const float* b0     = (const float*)d_in[4];
    const float* gcn_W  = (const float*)d_in[5];
    const float* gcn_b  = (const float*)d_in[6];
    const float* lt1_W  = (const float*)d_in[7];
    const float* lt1_b  = (const float*)d_in[8];
    float* out = (float*)d_out;

    const int N = in_sizes[0] / FDIM;
    const int E = in_sizes[1] / 2;
    const int L = in_sizes[5] / (FDIM * FDIM);
    const int C = in_sizes[7] / FDIM;

    // carve workspace
    char* p = (char*)d_ws;
    auto alloc = [&](size_t bytes) {
        void* r = (void*)p;
        p += (bytes + 255) / 256 * 256;
        return r;
    };
    float* new_w0 = (float*)alloc(FDIM * FDIM * 4);
    int*   counts = (int*)alloc((size_t)N * 4);
    int*   rowptr = (int*)alloc((size_t)(N + 1) * 4);
    float* dis    = (float*)alloc((size_t)N * 4);
    int*   csrs   = (int*)alloc((size_t)E * 4);
    float* csrw   = (float*)alloc((size_t)E * 4);
    float* hA     = (float*)alloc((size_t)N * FDIM * 4);
    float* hB     = (float*)alloc((size_t)N * FDIM * 4);

    // graph preprocessing
    k_new_w0<<<FDIM, FDIM, 0, stream>>>(w0, E_meta, b0, new_w0);
    k_zero<<<(N + 255) / 256, 256, 0, stream>>>(counts, N);
    k_count<<<(E + 255) / 256, 256, 0, stream>>>(ei, counts, E);
    k_scan<<<1, 1024, 0, stream>>>(counts, rowptr, dis, N);
    k_scatter<<<(E + 255) / 256, 256, 0, stream>>>(ei, rowptr, counts, dis, csrs, csrw, E);

    int gemm_grid = (N + BM - 1) / BM;
    // h0 = x @ new_w0
    k_gemm<<<gemm_grid, 256, 0, stream>>>(x, new_w0, nullptr, hA, N);
    // GCN layers
    for (int l = 0; l < L; l++) {
        k_gemm<<<gemm_grid, 256, 0, stream>>>(hA, gcn_W + (size_t)l * FDIM * FDIM,
                                              gcn_b + (size_t)l * FDIM, hB, N);
        dim3 ablk(32, 8);
        k_aggregate<<<(N + 7) / 8, ablk, 0, stream>>>(hB, rowptr, csrs, csrw, dis, hA, N);
    }
    // logits + log_softmax
    k_final<<<1024, 256, 0, stream>>>(hA, lt1_W, lt1_b, out, N, C);
}

// Round 2
// 407.738 us; speedup vs baseline: 1.3805x; 1.3805x over previous
//
#include <hip/hip_runtime.h>
#include <math.h>

#define FDIM 128

typedef short s16x8 __attribute__((ext_vector_type(8)));
typedef float f32x4 __attribute__((ext_vector_type(4)));

__device__ __forceinline__ ushort f2bf(float f) {
    union { float f; unsigned u; } v; v.f = f;
    unsigned u = v.u;
    unsigned r = (u + 0x7FFFu + ((u >> 16) & 1u)) >> 16;
    return (ushort)r;
}
__device__ __forceinline__ float bf2f(ushort b) {
    union { unsigned u; float f; } v; v.u = ((unsigned)b) << 16;
    return v.f;
}

// ---------------- WT0[c][k] = relu(w0[k]*Em[c] + b0[k][c]), bf16 -----------------
__global__ void k_new_w0t(const float* __restrict__ w0, const float* __restrict__ Em,
                          const float* __restrict__ b0, ushort* __restrict__ WT0) {
    int c = blockIdx.x, k = threadIdx.x;
    float v = w0[k] * Em[c] + b0[k * FDIM + c];
    WT0[c * FDIM + k] = f2bf(v > 0.f ? v : 0.f);
}

// ---------------- WT[l][c][k] = bf16(W[l][k][c]) -----------------
__global__ void k_transpose_w(const float* __restrict__ W, ushort* __restrict__ WT) {
    int b = blockIdx.x;            // l*128 + c
    int l = b >> 7, c = b & 127;
    int k = threadIdx.x;
    WT[(size_t)l * FDIM * FDIM + c * FDIM + k] = f2bf(W[(size_t)l * FDIM * FDIM + k * FDIM + c]);
}

// ---------------- zero int buffer -----------------
__global__ void k_zero(int* __restrict__ p, int n) {
    int i = blockIdx.x * 256 + threadIdx.x;
    if (i < n) p[i] = 0;
}

// ---------------- per-dst degree count -----------------
__global__ void k_count(const int* __restrict__ ei, int* __restrict__ counts, int E) {
    int e = blockIdx.x * 256 + threadIdx.x;
    if (e < E) atomicAdd(&counts[ei[E + e]], 1);
}

// ---------------- scan phase 1: per-block (1024 elems) sums -----------------
__global__ __launch_bounds__(256) void k_blocksum(const int* __restrict__ counts,
                                                  int* __restrict__ partials, int n4) {
    int t = blockIdx.x * 256 + threadIdx.x;
    int4 c = (t < n4) ? ((const int4*)counts)[t] : make_int4(0, 0, 0, 0);
    int s = c.x + c.y + c.z + c.w;
    for (int off = 1; off < 64; off <<= 1) s += __shfl_xor(s, off);
    __shared__ int ws[4];
    if ((threadIdx.x & 63) == 0) ws[threadIdx.x >> 6] = s;
    __syncthreads();
    if (threadIdx.x == 0) partials[blockIdx.x] = ws[0] + ws[1] + ws[2] + ws[3];
}

// ---------------- scan phase 2: exclusive scan of <=64 partials (1 wave) ------------
__global__ void k_scanpart(int* __restrict__ partials, int nb,
                           int* __restrict__ rowptr, int N, int E) {
    int l = threadIdx.x;
    int v = (l < nb) ? partials[l] : 0;
    int s = v;
    for (int off = 1; off < 64; off <<= 1) {
        int t = __shfl_up(s, off);
        if (l >= off) s += t;
    }
    if (l < nb) partials[l] = s - v;
    if (l == 0) rowptr[N] = E;
}

// ---------------- scan phase 3: local scan + offset; write rowptr/dis, zero counts ----
__global__ __launch_bounds__(256) void k_scanfinal(int* __restrict__ counts,
                                                   const int* __restrict__ partials,
                                                   int* __restrict__ rowptr,
                                                   float* __restrict__ dis, int n4) {
    int tid = threadIdx.x;
    int t = blockIdx.x * 256 + tid;
    int4 c = (t < n4) ? ((const int4*)counts)[t] : make_int4(0, 0, 0, 0);
    int s = c.x + c.y + c.z + c.w;
    int lane = tid & 63, wave = tid >> 6;
    int incl = s;
    for (int off = 1; off < 64; off <<= 1) {
        int tv = __shfl_up(incl, off);
        if (lane >= off) incl += tv;
    }
    __shared__ int wt[4];
    if (lane == 63) wt[wave] = incl;
    __syncthreads();
    int base = partials[blockIdx.x];
    for (int w = 0; w < wave; w++) base += wt[w];
    int excl = base + incl - s;
    if (t < n4) {
        ((int4*)rowptr)[t] = make_int4(excl, excl + c.x, excl + c.x + c.y, excl + c.x + c.y + c.z);
        float4 dv;
        dv.x = rsqrtf((float)c.x + 1.f); dv.y = rsqrtf((float)c.y + 1.f);
        dv.z = rsqrtf((float)c.z + 1.f); dv.w = rsqrtf((float)c.w + 1.f);
        ((float4*)dis)[t] = dv;
        ((int4*)counts)[t] = make_int4(0, 0, 0, 0);
    }
}

// ---------------- scatter edges into CSR (by dst) -----------------
__global__ void k_scatter(const int* __restrict__ ei, const int* __restrict__ rowptr,
                          int* __restrict__ cursor, const float* __restrict__ dis,
                          int* __restrict__ csr_src, float* __restrict__ csr_w, int E) {
    int e = blockIdx.x * 256 + threadIdx.x;
    if (e >= E) return;
    int s = ei[e], d = ei[E + e];
    int pos = atomicAdd(&cursor[d], 1);
    int j = rowptr[d] + pos;
    csr_src[j] = s;
    csr_w[j] = dis[s] * dis[d];
}

// ------------- MFMA GEMM: C[n,128](bf16) = A[n,128] @ WT^T (+bias) ----------------
// WT is [128 c][128 k] bf16.  A_FP32 selects fp32 vs bf16 A source.
template <int A_FP32>
__global__ __launch_bounds__(256) void k_gemm_mfma(const void* __restrict__ Ain,
                                                   const ushort* __restrict__ WT,
                                                   const float* __restrict__ bias,
                                                   ushort* __restrict__ Cout, int n) {
    __shared__ ushort As[64 * FDIM];    // 16 KB, XOR-swizzled 16B chunks
    __shared__ ushort Bs[FDIM * FDIM];  // 32 KB, XOR-swizzled
    int tid = threadIdx.x;
    int row0 = blockIdx.x * 64;

    // stage B: 128 rows x 16 chunks of 16B
    {
        const uint4* src = (const uint4*)WT;
        for (int t = tid; t < 2048; t += 256) {
            int r = t >> 4, ch = t & 15;
            uint4 v = src[t];
            *(uint4*)&Bs[r * FDIM + (ch ^ (r & 7)) * 8] = v;
        }
    }
    // stage A: 64 rows
    if (A_FP32) {
        const float4* src = (const float4*)Ain;  // 32 float4 per row
        for (int t = tid; t < 1024; t += 256) {
            int r = t >> 4, c4 = t & 15;          // c4: 8 elems? no: float4 = 4 elems, 16 per row... t&15 covers 16 of 32
            // two passes folded: each t handles TWO float4 (front/back half of row)
            int row = row0 + r;
            float4 v0 = make_float4(0, 0, 0, 0), v1 = make_float4(0, 0, 0, 0);
            if (row < n) {
                v0 = src[row * 32 + c4 * 2];
                v1 = src[row * 32 + c4 * 2 + 1];
            }
            ushort4 b0, b1;
            b0.x = f2bf(v0.x); b0.y = f2bf(v0.y); b0.z = f2bf(v0.z); b0.w = f2bf(v0.w);
            b1.x = f2bf(v1.x); b1.y = f2bf(v1.y); b1.z = f2bf(v1.z); b1.w = f2bf(v1.w);
            int chs = (c4 ^ (r & 7)) * 8;
            *(ushort4*)&As[r * FDIM + chs] = b0;
            *(ushort4*)&As[r * FDIM + chs + 4] = b1;
        }
    } else {
        const uint4* src = (const uint4*)Ain;  // 16 chunks per row
        for (int t = tid; t < 1024; t += 256) {
            int r = t >> 4, ch = t & 15;
            int row = row0 + r;
            uint4 v = make_uint4(0, 0, 0, 0);
            if (row < n) v = src[row * 16 + ch];
            *(uint4*)&As[r * FDIM + (ch ^ (r & 7)) * 8] = v;
        }
    }
    __syncthreads();

    int wave = tid >> 6, lane = tid & 63;
    int lr = lane & 15, lg = lane >> 4;
    f32x4 acc[8];
#pragma unroll
    for (int i = 0; i < 8; i++) acc[i] = (f32x4){0.f, 0.f, 0.f, 0.f};

#pragma unroll
    for (int k0 = 0; k0 < 4; k0++) {
        int kch = k0 * 4 + lg;   // 16B chunk index along k
        int ar = wave * 16 + lr;
        s16x8 a = *(const s16x8*)&As[ar * FDIM + (kch ^ (ar & 7)) * 8];
#pragma unroll
        for (int ct = 0; ct < 8; ct++) {
            int bc = ct * 16 + lr;
            s16x8 b = *(const s16x8*)&Bs[bc * FDIM + (kch ^ (bc & 7)) * 8];
            acc[ct] = __builtin_amdgcn_mfma_f32_16x16x32_bf16(a, b, acc[ct], 0, 0, 0);
        }
    }
    // epilogue: row = wave*16 + lg*4 + r, col = ct*16 + lr
#pragma unroll
    for (int ct = 0; ct < 8; ct++) {
        int col = ct * 16 + lr;
        float bv = bias ? bias[col] : 0.f;
#pragma unroll
        for (int r = 0; r < 4; r++) {
            int row = row0 + wave * 16 + lg * 4 + r;
            if (row < n) Cout[(size_t)row * FDIM + col] = f2bf(acc[ct][r] + bv);
        }
    }
}

// ------------- aggregate: h = relu(gather(hw)*w + hw*sn), bf16 in/out -------------
__global__ __launch_bounds__(256) void k_aggregate(const ushort* __restrict__ hw,
                                                   const int* __restrict__ rowptr,
                                                   const int* __restrict__ csr_src,
                                                   const float* __restrict__ csr_w,
                                                   const float* __restrict__ dis,
                                                   ushort* __restrict__ h, int n) {
    int node = blockIdx.x * 8 + threadIdx.y;
    if (node >= n) return;
    int q = threadIdx.x;  // 0..31, features q*4..q*4+3
    const ushort4* hv = (const ushort4*)hw;
    float d = dis[node];
    float sn = d * d;
    ushort4 s4 = hv[node * 32 + q];
    float ax = bf2f(s4.x) * sn, ay = bf2f(s4.y) * sn, az = bf2f(s4.z) * sn, aw = bf2f(s4.w) * sn;
    int j = rowptr[node], end = rowptr[node + 1];
    int s = 0; float w = 0.f;
    if (j < end) { s = csr_src[j]; w = csr_w[j]; }
    while (j < end) {
        int jn = j + 1;
        int s2 = 0; float w2 = 0.f;
        if (jn < end) { s2 = csr_src[jn]; w2 = csr_w[jn]; }
        ushort4 v = hv[s * 32 + q];
        ax += bf2f(v.x) * w; ay += bf2f(v.y) * w;
        az += bf2f(v.z) * w; aw += bf2f(v.w) * w;
        s = s2; w = w2; j = jn;
    }
    ushort4 o;
    o.x = f2bf(fmaxf(ax, 0.f)); o.y = f2bf(fmaxf(ay, 0.f));
    o.z = f2bf(fmaxf(az, 0.f)); o.w = f2bf(fmaxf(aw, 0.f));
    ((ushort4*)h)[node * 32 + q] = o;
}

// ---------------- final: logits = h @ lt1_W + b; log_softmax ----------------
__global__ __launch_bounds__(256) void k_final(const ushort* __restrict__ h,
                                               const float* __restrict__ W,
                                               const float* __restrict__ bias,
                                               float* __restrict__ out, int n, int C) {
    __shared__ float Ws[FDIM * 40];
    __shared__ float hs[4][FDIM];
    int tid = threadIdx.x;
    for (int t = tid; t < FDIM * C; t += 256) Ws[t] = W[t];
    __syncthreads();
    int wave = tid >> 6, lane = tid & 63;
    int c = (lane < C) ? lane : 0;
    float b = bias[c];
    int gw = blockIdx.x * 4 + wave;
    int nw = gridDim.x * 4;
    const unsigned* hu = (const unsigned*)h;  // 64 uints (2 bf16) per row
    for (int node = gw; node < n; node += nw) {
        unsigned v2 = hu[node * 64 + lane];
        hs[wave][lane * 2] = bf2f((ushort)(v2 & 0xFFFF));
        hs[wave][lane * 2 + 1] = bf2f((ushort)(v2 >> 16));
        float acc = 0.f;
#pragma unroll 8
        for (int k = 0; k < FDIM; k++) acc += hs[wave][k] * Ws[k * C + c];
        float logit = acc + b;
        float v = (lane < C) ? logit : -1e30f;
        float m = v;
        for (int off = 32; off; off >>= 1) m = fmaxf(m, __shfl_xor(m, off));
        float e = (lane < C) ? expf(logit - m) : 0.f;
        float ssum = e;
        for (int off = 32; off; off >>= 1) ssum += __shfl_xor(ssum, off);
        if (lane < C) out[node * C + lane] = logit - m - logf(ssum);
    }
}

extern "C" void kernel_launch(void* const* d_in, const int* in_sizes, int n_in,
                              void* d_out, int out_size, void* d_ws, size_t ws_size,
                              hipStream_t stream) {
    const float* x      = (const float*)d_in[0];
    const int*   ei     = (const int*)d_in[1];
    const float* E_meta = (const float*)d_in[2];
    const float* w0     = (const float*)d_in[3];
    const float* b0     = (const float*)d_in[4];
    const float* gcn_W  = (const float*)d_in[5];
    const float* gcn_b  = (const float*)d_in[6];
    const float* lt1_W  = (const float*)d_in[7];
    const float* lt1_b  = (const float*)d_in[8];
    float* out = (float*)d_out;

    const int N = in_sizes[0] / FDIM;
    const int E = in_sizes[1] / 2;
    const int L = in_sizes[5] / (FDIM * FDIM);
    const int C = in_sizes[7] / FDIM;

    char* p = (char*)d_ws;
    auto alloc = [&](size_t bytes) {
        void* r = (void*)p;
        p += (bytes + 255) / 256 * 256;
        return r;
    };
    ushort* WT0    = (ushort*)alloc((size_t)FDIM * FDIM * 2);
    ushort* WTl    = (ushort*)alloc((size_t)L * FDIM * FDIM * 2);
    int*    counts = (int*)alloc((size_t)N * 4);
    int*    rowptr = (int*)alloc((size_t)(N + 1) * 4);
    float*  dis    = (float*)alloc((size_t)N * 4);
    int*    parts  = (int*)alloc(64 * 4);
    int*    csrs   = (int*)alloc((size_t)E * 4);
    float*  csrw   = (float*)alloc((size_t)E * 4);
    ushort* hA     = (ushort*)alloc((size_t)N * FDIM * 2);
    ushort* hB     = (ushort*)alloc((size_t)N * FDIM * 2);

    const int n4 = N / 4;                       // N divisible by 4 (50000)
    const int nb = (n4 + 255) / 256;            // scan blocks (1024 elems each)

    // weight prep
    k_new_w0t<<<FDIM, FDIM, 0, stream>>>(w0, E_meta, b0, WT0);
    k_transpose_w<<<L * FDIM, FDIM, 0, stream>>>(gcn_W, WTl);

    // graph preprocessing
    k_zero<<<(N + 255) / 256, 256, 0, stream>>>(counts, N);
    k_count<<<(E + 255) / 256, 256, 0, stream>>>(ei, counts, E);
    k_blocksum<<<nb, 256, 0, stream>>>(counts, parts, n4);
    k_scanpart<<<1, 64, 0, stream>>>(parts, nb, rowptr, N, E);
    k_scanfinal<<<nb, 256, 0, stream>>>(counts, parts, rowptr, dis, n4);
    k_scatter<<<(E + 255) / 256, 256, 0, stream>>>(ei, rowptr, counts, dis, csrs, csrw, E);

    int gemm_grid = (N + 63) / 64;
    // h0 = x @ new_w0  (fp32 A)
    k_gemm_mfma<1><<<gemm_grid, 256, 0, stream>>>(x, WT0, nullptr, hA, N);
    // GCN layers
    for (int l = 0; l < L; l++) {
        k_gemm_mfma<0><<<gemm_grid, 256, 0, stream>>>(hA, WTl + (size_t)l * FDIM * FDIM,
                                                      gcn_b + (size_t)l * FDIM, hB, N);
        dim3 ablk(32, 8);
        k_aggregate<<<(N + 7) / 8, ablk, 0, stream>>>(hB, rowptr, csrs, csrw, dis, hA, N);
    }
    k_final<<<1024, 256, 0, stream>>>(hA, lt1_W, lt1_b, out, N, C);
}

// Round 3
// 359.919 us; speedup vs baseline: 1.5639x; 1.1329x over previous
//
#include <hip/hip_runtime.h>
#include <math.h>

#define FDIM 128

typedef short s16x8 __attribute__((ext_vector_type(8)));
typedef float f32x4 __attribute__((ext_vector_type(4)));

__device__ __forceinline__ ushort f2bf(float f) {
    union { float f; unsigned u; } v; v.f = f;
    unsigned u = v.u;
    unsigned r = (u + 0x7FFFu + ((u >> 16) & 1u)) >> 16;
    return (ushort)r;
}
__device__ __forceinline__ float bf2f(ushort b) {
    union { unsigned u; float f; } v; v.u = ((unsigned)b) << 16;
    return v.f;
}

// ---------------- WT0[c][k] = relu(w0[k]*Em[c] + b0[k][c]), bf16 -----------------
__global__ void k_new_w0t(const float* __restrict__ w0, const float* __restrict__ Em,
                          const float* __restrict__ b0, ushort* __restrict__ WT0) {
    int c = blockIdx.x, k = threadIdx.x;
    float v = w0[k] * Em[c] + b0[k * FDIM + c];
    WT0[c * FDIM + k] = f2bf(v > 0.f ? v : 0.f);
}

// ---------------- WT[l][c][k] = bf16(W[l][k][c]) -----------------
__global__ void k_transpose_w(const float* __restrict__ W, ushort* __restrict__ WT) {
    int b = blockIdx.x;            // l*128 + c
    int l = b >> 7, c = b & 127;
    int k = threadIdx.x;
    WT[(size_t)l * FDIM * FDIM + c * FDIM + k] = f2bf(W[(size_t)l * FDIM * FDIM + k * FDIM + c]);
}

// ---------------- WTf[c][k] = bf16(lt1_W[k][c]) for c<40 else 0; [48][128] --------
__global__ void k_prep_wtf(const float* __restrict__ W, ushort* __restrict__ WTf, int C) {
    int c = blockIdx.x, k = threadIdx.x;
    WTf[c * FDIM + k] = (c < C) ? f2bf(W[k * C + c]) : (ushort)0;
}

// ---------------- zero int buffer -----------------
__global__ void k_zero(int* __restrict__ p, int n) {
    int i = blockIdx.x * 256 + threadIdx.x;
    if (i < n) p[i] = 0;
}

// ---------------- per-dst degree count -----------------
__global__ void k_count(const int* __restrict__ ei, int* __restrict__ counts, int E) {
    int e = blockIdx.x * 256 + threadIdx.x;
    if (e < E) atomicAdd(&counts[ei[E + e]], 1);
}

// ---------------- scan phase 1: per-block (1024 elems) sums -----------------
__global__ __launch_bounds__(256) void k_blocksum(const int* __restrict__ counts,
                                                  int* __restrict__ partials, int n4) {
    int t = blockIdx.x * 256 + threadIdx.x;
    int4 c = (t < n4) ? ((const int4*)counts)[t] : make_int4(0, 0, 0, 0);
    int s = c.x + c.y + c.z + c.w;
    for (int off = 1; off < 64; off <<= 1) s += __shfl_xor(s, off);
    __shared__ int ws[4];
    if ((threadIdx.x & 63) == 0) ws[threadIdx.x >> 6] = s;
    __syncthreads();
    if (threadIdx.x == 0) partials[blockIdx.x] = ws[0] + ws[1] + ws[2] + ws[3];
}

// ---------------- scan phase 2: exclusive scan of <=64 partials (1 wave) ------------
__global__ void k_scanpart(int* __restrict__ partials, int nb,
                           int* __restrict__ rowptr, int N, int E) {
    int l = threadIdx.x;
    int v = (l < nb) ? partials[l] : 0;
    int s = v;
    for (int off = 1; off < 64; off <<= 1) {
        int t = __shfl_up(s, off);
        if (l >= off) s += t;
    }
    if (l < nb) partials[l] = s - v;
    if (l == 0) rowptr[N] = E;
}

// ---------------- scan phase 3: local scan + offset; write rowptr/dis, zero counts ----
__global__ __launch_bounds__(256) void k_scanfinal(int* __restrict__ counts,
                                                   const int* __restrict__ partials,
                                                   int* __restrict__ rowptr,
                                                   float* __restrict__ dis, int n4) {
    int tid = threadIdx.x;
    int t = blockIdx.x * 256 + tid;
    int4 c = (t < n4) ? ((const int4*)counts)[t] : make_int4(0, 0, 0, 0);
    int s = c.x + c.y + c.z + c.w;
    int lane = tid & 63, wave = tid >> 6;
    int incl = s;
    for (int off = 1; off < 64; off <<= 1) {
        int tv = __shfl_up(incl, off);
        if (lane >= off) incl += tv;
    }
    __shared__ int wt[4];
    if (lane == 63) wt[wave] = incl;
    __syncthreads();
    int base = partials[blockIdx.x];
    for (int w = 0; w < wave; w++) base += wt[w];
    int excl = base + incl - s;
    if (t < n4) {
        ((int4*)rowptr)[t] = make_int4(excl, excl + c.x, excl + c.x + c.y, excl + c.x + c.y + c.z);
        float4 dv;
        dv.x = rsqrtf((float)c.x + 1.f); dv.y = rsqrtf((float)c.y + 1.f);
        dv.z = rsqrtf((float)c.z + 1.f); dv.w = rsqrtf((float)c.w + 1.f);
        ((float4*)dis)[t] = dv;
        ((int4*)counts)[t] = make_int4(0, 0, 0, 0);
    }
}

// ---------------- scatter edges into CSR (by dst) -----------------
__global__ void k_scatter(const int* __restrict__ ei, const int* __restrict__ rowptr,
                          int* __restrict__ cursor, const float* __restrict__ dis,
                          int* __restrict__ csr_src, float* __restrict__ csr_w, int E) {
    int e = blockIdx.x * 256 + threadIdx.x;
    if (e >= E) return;
    int s = ei[e], d = ei[E + e];
    int pos = atomicAdd(&cursor[d], 1);
    int j = rowptr[d] + pos;
    csr_src[j] = s;
    csr_w[j] = dis[s] * dis[d];
}

// ------------- MFMA GEMM: C[n,128](bf16) = A[n,128] @ WT^T (+bias) ----------------
// WT is [128 c][128 k] bf16.  A_FP32 selects fp32 vs bf16 A source.
template <int A_FP32>
__global__ __launch_bounds__(256) void k_gemm_mfma(const void* __restrict__ Ain,
                                                   const ushort* __restrict__ WT,
                                                   const float* __restrict__ bias,
                                                   ushort* __restrict__ Cout, int n) {
    __shared__ ushort As[64 * FDIM];    // 16 KB, XOR-swizzled 16B chunks
    __shared__ ushort Bs[FDIM * FDIM];  // 32 KB, XOR-swizzled
    int tid = threadIdx.x;
    int row0 = blockIdx.x * 64;

    // stage B: 128 rows x 16 chunks of 16B
    {
        const uint4* src = (const uint4*)WT;
        for (int t = tid; t < 2048; t += 256) {
            int r = t >> 4, ch = t & 15;
            uint4 v = src[t];
            *(uint4*)&Bs[r * FDIM + (ch ^ (r & 7)) * 8] = v;
        }
    }
    // stage A: 64 rows
    if (A_FP32) {
        const float4* src = (const float4*)Ain;  // 32 float4 per row
        for (int t = tid; t < 1024; t += 256) {
            int r = t >> 4, c4 = t & 15;
            int row = row0 + r;
            float4 v0 = make_float4(0, 0, 0, 0), v1 = make_float4(0, 0, 0, 0);
            if (row < n) {
                v0 = src[row * 32 + c4 * 2];
                v1 = src[row * 32 + c4 * 2 + 1];
            }
            ushort4 b0, b1;
            b0.x = f2bf(v0.x); b0.y = f2bf(v0.y); b0.z = f2bf(v0.z); b0.w = f2bf(v0.w);
            b1.x = f2bf(v1.x); b1.y = f2bf(v1.y); b1.z = f2bf(v1.z); b1.w = f2bf(v1.w);
            int chs = (c4 ^ (r & 7)) * 8;
            *(ushort4*)&As[r * FDIM + chs] = b0;
            *(ushort4*)&As[r * FDIM + chs + 4] = b1;
        }
    } else {
        const uint4* src = (const uint4*)Ain;  // 16 chunks per row
        for (int t = tid; t < 1024; t += 256) {
            int r = t >> 4, ch = t & 15;
            int row = row0 + r;
            uint4 v = make_uint4(0, 0, 0, 0);
            if (row < n) v = src[row * 16 + ch];
            *(uint4*)&As[r * FDIM + (ch ^ (r & 7)) * 8] = v;
        }
    }
    __syncthreads();

    int wave = tid >> 6, lane = tid & 63;
    int lr = lane & 15, lg = lane >> 4;
    f32x4 acc[8];
#pragma unroll
    for (int i = 0; i < 8; i++) acc[i] = (f32x4){0.f, 0.f, 0.f, 0.f};

#pragma unroll
    for (int k0 = 0; k0 < 4; k0++) {
        int kch = k0 * 4 + lg;   // 16B chunk index along k
        int ar = wave * 16 + lr;
        s16x8 a = *(const s16x8*)&As[ar * FDIM + (kch ^ (ar & 7)) * 8];
#pragma unroll
        for (int ct = 0; ct < 8; ct++) {
            int bc = ct * 16 + lr;
            s16x8 b = *(const s16x8*)&Bs[bc * FDIM + (kch ^ (bc & 7)) * 8];
            acc[ct] = __builtin_amdgcn_mfma_f32_16x16x32_bf16(a, b, acc[ct], 0, 0, 0);
        }
    }
    // epilogue: row = wave*16 + lg*4 + r, col = ct*16 + lr
#pragma unroll
    for (int ct = 0; ct < 8; ct++) {
        int col = ct * 16 + lr;
        float bv = bias ? bias[col] : 0.f;
#pragma unroll
        for (int r = 0; r < 4; r++) {
            int row = row0 + wave * 16 + lg * 4 + r;
            if (row < n) Cout[(size_t)row * FDIM + col] = f2bf(acc[ct][r] + bv);
        }
    }
}

// ------------- aggregate: h = relu(gather(hw)*w + hw*sn), bf16 in/out -------------
__global__ __launch_bounds__(256) void k_aggregate(const ushort* __restrict__ hw,
                                                   const int* __restrict__ rowptr,
                                                   const int* __restrict__ csr_src,
                                                   const float* __restrict__ csr_w,
                                                   const float* __restrict__ dis,
                                                   ushort* __restrict__ h, int n) {
    int node = blockIdx.x * 8 + threadIdx.y;
    if (node >= n) return;
    int q = threadIdx.x;  // 0..31, features q*4..q*4+3
    const ushort4* hv = (const ushort4*)hw;
    float d = dis[node];
    float sn = d * d;
    ushort4 s4 = hv[node * 32 + q];
    float ax = bf2f(s4.x) * sn, ay = bf2f(s4.y) * sn, az = bf2f(s4.z) * sn, aw = bf2f(s4.w) * sn;
    int j = rowptr[node], end = rowptr[node + 1];
    int s = 0; float w = 0.f;
    if (j < end) { s = csr_src[j]; w = csr_w[j]; }
    while (j < end) {
        int jn = j + 1;
        int s2 = 0; float w2 = 0.f;
        if (jn < end) { s2 = csr_src[jn]; w2 = csr_w[jn]; }
        ushort4 v = hv[s * 32 + q];
        ax += bf2f(v.x) * w; ay += bf2f(v.y) * w;
        az += bf2f(v.z) * w; aw += bf2f(v.w) * w;
        s = s2; w = w2; j = jn;
    }
    ushort4 o;
    o.x = f2bf(fmaxf(ax, 0.f)); o.y = f2bf(fmaxf(ay, 0.f));
    o.z = f2bf(fmaxf(az, 0.f)); o.w = f2bf(fmaxf(aw, 0.f));
    ((ushort4*)h)[node * 32 + q] = o;
}

// ------- final: logits = h @ lt1_W + b via MFMA; out = log_softmax(logits) --------
// WTf is [48][128] bf16 (cols 40..47 zero).
__global__ __launch_bounds__(256) void k_final_mfma(const ushort* __restrict__ h,
                                                    const ushort* __restrict__ WTf,
                                                    const float* __restrict__ bias,
                                                    float* __restrict__ out, int n, int C) {
    __shared__ ushort As[64 * FDIM];   // 16 KB
    __shared__ ushort Bs[48 * FDIM];   // 12 KB
    int tid = threadIdx.x;
    int row0 = blockIdx.x * 64;

    // stage B: 48 rows x 16 chunks
    {
        const uint4* src = (const uint4*)WTf;
        for (int t = tid; t < 768; t += 256) {
            int r = t >> 4, ch = t & 15;
            uint4 v = src[t];
            *(uint4*)&Bs[r * FDIM + (ch ^ (r & 7)) * 8] = v;
        }
    }
    // stage A: 64 rows of h (bf16)
    {
        const uint4* src = (const uint4*)h;
        for (int t = tid; t < 1024; t += 256) {
            int r = t >> 4, ch = t & 15;
            int row = row0 + r;
            uint4 v = make_uint4(0, 0, 0, 0);
            if (row < n) v = src[row * 16 + ch];
            *(uint4*)&As[r * FDIM + (ch ^ (r & 7)) * 8] = v;
        }
    }
    __syncthreads();

    int wave = tid >> 6, lane = tid & 63;
    int lr = lane & 15, lg = lane >> 4;
    f32x4 acc[3];
#pragma unroll
    for (int i = 0; i < 3; i++) acc[i] = (f32x4){0.f, 0.f, 0.f, 0.f};

#pragma unroll
    for (int k0 = 0; k0 < 4; k0++) {
        int kch = k0 * 4 + lg;
        int ar = wave * 16 + lr;
        s16x8 a = *(const s16x8*)&As[ar * FDIM + (kch ^ (ar & 7)) * 8];
#pragma unroll
        for (int ct = 0; ct < 3; ct++) {
            int bc = ct * 16 + lr;
            s16x8 b = *(const s16x8*)&Bs[bc * FDIM + (kch ^ (bc & 7)) * 8];
            acc[ct] = __builtin_amdgcn_mfma_f32_16x16x32_bf16(a, b, acc[ct], 0, 0, 0);
        }
    }

    // bias per lane per column tile; invalid cols get 0 (masked below)
    float bv[3];
#pragma unroll
    for (int ct = 0; ct < 3; ct++) {
        int col = ct * 16 + lr;
        bv[ct] = (col < C) ? bias[col] : 0.f;
    }
    bool v2ok = (32 + lr) < C;  // ct==2 validity (cols 32..47)

    // per accumulator reg r: row = wave*16 + lg*4 + r; softmax over 48 cols (mask >=C)
#pragma unroll
    for (int r = 0; r < 4; r++) {
        float l0 = acc[0][r] + bv[0];
        float l1 = acc[1][r] + bv[1];
        float l2 = acc[2][r] + bv[2];
        float m = fmaxf(l0, l1);
        if (v2ok) m = fmaxf(m, l2);
#pragma unroll
        for (int off = 1; off < 16; off <<= 1) m = fmaxf(m, __shfl_xor(m, off));
        float e = __expf(l0 - m) + __expf(l1 - m) + (v2ok ? __expf(l2 - m) : 0.f);
#pragma unroll
        for (int off = 1; off < 16; off <<= 1) e += __shfl_xor(e, off);
        float lse = m + __logf(e);
        int row = row0 + wave * 16 + lg * 4 + r;
        if (row < n) {
            out[(size_t)row * C + lr] = l0 - lse;
            out[(size_t)row * C + 16 + lr] = l1 - lse;
            if (v2ok) out[(size_t)row * C + 32 + lr] = l2 - lse;
        }
    }
}

extern "C" void kernel_launch(void* const* d_in, const int* in_sizes, int n_in,
                              void* d_out, int out_size, void* d_ws, size_t ws_size,
                              hipStream_t stream) {
    const float* x      = (const float*)d_in[0];
    const int*   ei     = (const int*)d_in[1];
    const float* E_meta = (const float*)d_in[2];
    const float* w0     = (const float*)d_in[3];
    const float* b0     = (const float*)d_in[4];
    const float* gcn_W  = (const float*)d_in[5];
    const float* gcn_b  = (const float*)d_in[6];
    const float* lt1_W  = (const float*)d_in[7];
    const float* lt1_b  = (const float*)d_in[8];
    float* out = (float*)d_out;

    const int N = in_sizes[0] / FDIM;
    const int E = in_sizes[1] / 2;
    const int L = in_sizes[5] / (FDIM * FDIM);
    const int C = in_sizes[7] / FDIM;

    char* p = (char*)d_ws;
    auto alloc = [&](size_t bytes) {
        void* r = (void*)p;
        p += (bytes + 255) / 256 * 256;
        return r;
    };
    ushort* WT0    = (ushort*)alloc((size_t)FDIM * FDIM * 2);
    ushort* WTl    = (ushort*)alloc((size_t)L * FDIM * FDIM * 2);
    ushort* WTf    = (ushort*)alloc((size_t)48 * FDIM * 2);
    int*    counts = (int*)alloc((size_t)N * 4);
    int*    rowptr = (int*)alloc((size_t)(N + 1) * 4);
    float*  dis    = (float*)alloc((size_t)N * 4);
    int*    parts  = (int*)alloc(64 * 4);
    int*    csrs   = (int*)alloc((size_t)E * 4);
    float*  csrw   = (float*)alloc((size_t)E * 4);
    ushort* hA     = (ushort*)alloc((size_t)N * FDIM * 2);
    ushort* hB     = (ushort*)alloc((size_t)N * FDIM * 2);

    const int n4 = N / 4;                       // N divisible by 4 (50000)
    const int nb = (n4 + 255) / 256;            // scan blocks (1024 elems each)

    // weight prep
    k_new_w0t<<<FDIM, FDIM, 0, stream>>>(w0, E_meta, b0, WT0);
    k_transpose_w<<<L * FDIM, FDIM, 0, stream>>>(gcn_W, WTl);
    k_prep_wtf<<<48, FDIM, 0, stream>>>(lt1_W, WTf, C);

    // graph preprocessing
    k_zero<<<(N + 255) / 256, 256, 0, stream>>>(counts, N);
    k_count<<<(E + 255) / 256, 256, 0, stream>>>(ei, counts, E);
    k_blocksum<<<nb, 256, 0, stream>>>(counts, parts, n4);
    k_scanpart<<<1, 64, 0, stream>>>(parts, nb, rowptr, N, E);
    k_scanfinal<<<nb, 256, 0, stream>>>(counts, parts, rowptr, dis, n4);
    k_scatter<<<(E + 255) / 256, 256, 0, stream>>>(ei, rowptr, counts, dis, csrs, csrw, E);

    int gemm_grid = (N + 63) / 64;
    // h0 = x @ new_w0  (fp32 A)
    k_gemm_mfma<1><<<gemm_grid, 256, 0, stream>>>(x, WT0, nullptr, hA, N);
    // GCN layers
    for (int l = 0; l < L; l++) {
        k_gemm_mfma<0><<<gemm_grid, 256, 0, stream>>>(hA, WTl + (size_t)l * FDIM * FDIM,
                                                      gcn_b + (size_t)l * FDIM, hB, N);
        dim3 ablk(32, 8);
        k_aggregate<<<(N + 7) / 8, ablk, 0, stream>>>(hB, rowptr, csrs, csrw, dis, hA, N);
    }
    k_final_mfma<<<gemm_grid, 256, 0, stream>>>(hA, WTf, lt1_b, out, N, C);
}

// Round 4
// 283.629 us; speedup vs baseline: 1.9845x; 1.2690x over previous
//
#include <hip/hip_runtime.h>
#include <math.h>

#define FDIM 128

typedef short s16x8 __attribute__((ext_vector_type(8)));
typedef float f32x4 __attribute__((ext_vector_type(4)));

__device__ __forceinline__ ushort f2bf(float f) {
    union { float f; unsigned u; } v; v.f = f;
    unsigned u = v.u;
    unsigned r = (u + 0x7FFFu + ((u >> 16) & 1u)) >> 16;
    return (ushort)r;
}
__device__ __forceinline__ float bf2f(ushort b) {
    union { unsigned u; float f; } v; v.u = ((unsigned)b) << 16;
    return v.f;
}

// ---------------- WT0[c][k] = relu(w0[k]*Em[c] + b0[k][c]), bf16 -----------------
__global__ void k_new_w0t(const float* __restrict__ w0, const float* __restrict__ Em,
                          const float* __restrict__ b0, ushort* __restrict__ WT0) {
    int c = blockIdx.x, k = threadIdx.x;
    float v = w0[k] * Em[c] + b0[k * FDIM + c];
    WT0[c * FDIM + k] = f2bf(v > 0.f ? v : 0.f);
}

// ---------------- WT[l][c][k] = bf16(W[l][k][c]) -----------------
__global__ void k_transpose_w(const float* __restrict__ W, ushort* __restrict__ WT) {
    int b = blockIdx.x;            // l*128 + c
    int l = b >> 7, c = b & 127;
    int k = threadIdx.x;
    WT[(size_t)l * FDIM * FDIM + c * FDIM + k] = f2bf(W[(size_t)l * FDIM * FDIM + k * FDIM + c]);
}

// ---------------- WTf[c][k] = bf16(lt1_W[k][c]) for c<40 else 0; [48][128] --------
__global__ void k_prep_wtf(const float* __restrict__ W, ushort* __restrict__ WTf, int C) {
    int c = blockIdx.x, k = threadIdx.x;
    WTf[c * FDIM + k] = (c < C) ? f2bf(W[k * C + c]) : (ushort)0;
}

// ---------------- zero int buffer -----------------
__global__ void k_zero(int* __restrict__ p, int n) {
    int i = blockIdx.x * 256 + threadIdx.x;
    if (i < n) p[i] = 0;
}

// ---------------- per-dst degree count -----------------
__global__ void k_count(const int* __restrict__ ei, int* __restrict__ counts, int E) {
    int e = blockIdx.x * 256 + threadIdx.x;
    if (e < E) atomicAdd(&counts[ei[E + e]], 1);
}

// ---------------- scan phase 1: per-block (1024 elems) sums -----------------
__global__ __launch_bounds__(256) void k_blocksum(const int* __restrict__ counts,
                                                  int* __restrict__ partials, int n4) {
    int t = blockIdx.x * 256 + threadIdx.x;
    int4 c = (t < n4) ? ((const int4*)counts)[t] : make_int4(0, 0, 0, 0);
    int s = c.x + c.y + c.z + c.w;
    for (int off = 1; off < 64; off <<= 1) s += __shfl_xor(s, off);
    __shared__ int ws[4];
    if ((threadIdx.x & 63) == 0) ws[threadIdx.x >> 6] = s;
    __syncthreads();
    if (threadIdx.x == 0) partials[blockIdx.x] = ws[0] + ws[1] + ws[2] + ws[3];
}

// ---------------- scan phase 2: exclusive scan of <=64 partials (1 wave) ------------
__global__ void k_scanpart(int* __restrict__ partials, int nb,
                           int* __restrict__ rowptr, int N, int E) {
    int l = threadIdx.x;
    int v = (l < nb) ? partials[l] : 0;
    int s = v;
    for (int off = 1; off < 64; off <<= 1) {
        int t = __shfl_up(s, off);
        if (l >= off) s += t;
    }
    if (l < nb) partials[l] = s - v;
    if (l == 0) rowptr[N] = E;
}

// ---------------- scan phase 3: local scan + offset; write rowptr/dis, zero counts ----
__global__ __launch_bounds__(256) void k_scanfinal(int* __restrict__ counts,
                                                   const int* __restrict__ partials,
                                                   int* __restrict__ rowptr,
                                                   float* __restrict__ dis, int n4) {
    int tid = threadIdx.x;
    int t = blockIdx.x * 256 + tid;
    int4 c = (t < n4) ? ((const int4*)counts)[t] : make_int4(0, 0, 0, 0);
    int s = c.x + c.y + c.z + c.w;
    int lane = tid & 63, wave = tid >> 6;
    int incl = s;
    for (int off = 1; off < 64; off <<= 1) {
        int tv = __shfl_up(incl, off);
        if (lane >= off) incl += tv;
    }
    __shared__ int wt[4];
    if (lane == 63) wt[wave] = incl;
    __syncthreads();
    int base = partials[blockIdx.x];
    for (int w = 0; w < wave; w++) base += wt[w];
    int excl = base + incl - s;
    if (t < n4) {
        ((int4*)rowptr)[t] = make_int4(excl, excl + c.x, excl + c.x + c.y, excl + c.x + c.y + c.z);
        float4 dv;
        dv.x = rsqrtf((float)c.x + 1.f); dv.y = rsqrtf((float)c.y + 1.f);
        dv.z = rsqrtf((float)c.z + 1.f); dv.w = rsqrtf((float)c.w + 1.f);
        ((float4*)dis)[t] = dv;
        ((int4*)counts)[t] = make_int4(0, 0, 0, 0);
    }
}

// ---------------- scatter edges into CSR (by dst), interleaved (src, w) -----------------
__global__ void k_scatter(const int* __restrict__ ei, const int* __restrict__ rowptr,
                          int* __restrict__ cursor, const float* __restrict__ dis,
                          int2* __restrict__ csr, int E) {
    int e = blockIdx.x * 256 + threadIdx.x;
    if (e >= E) return;
    int s = ei[e], d = ei[E + e];
    int pos = atomicAdd(&cursor[d], 1);
    int j = rowptr[d] + pos;
    float w = dis[s] * dis[d];
    csr[j] = make_int2(s, __float_as_int(w));
}

// ------------- MFMA GEMM: C[n,128](bf16) = A[n,128] @ WT^T (+bias) ----------------
// WT is [128 c][128 k] bf16.  A_FP32 selects fp32 vs bf16 A source.
template <int A_FP32>
__global__ __launch_bounds__(256) void k_gemm_mfma(const void* __restrict__ Ain,
                                                   const ushort* __restrict__ WT,
                                                   const float* __restrict__ bias,
                                                   ushort* __restrict__ Cout, int n) {
    __shared__ ushort As[64 * FDIM];    // 16 KB, XOR-swizzled 16B chunks
    __shared__ ushort Bs[FDIM * FDIM];  // 32 KB, XOR-swizzled
    int tid = threadIdx.x;
    int row0 = blockIdx.x * 64;

    // stage B: 128 rows x 16 chunks of 16B
    {
        const uint4* src = (const uint4*)WT;
        for (int t = tid; t < 2048; t += 256) {
            int r = t >> 4, ch = t & 15;
            uint4 v = src[t];
            *(uint4*)&Bs[r * FDIM + (ch ^ (r & 7)) * 8] = v;
        }
    }
    // stage A: 64 rows
    if (A_FP32) {
        const float4* src = (const float4*)Ain;  // 32 float4 per row
        for (int t = tid; t < 1024; t += 256) {
            int r = t >> 4, c4 = t & 15;
            int row = row0 + r;
            float4 v0 = make_float4(0, 0, 0, 0), v1 = make_float4(0, 0, 0, 0);
            if (row < n) {
                v0 = src[row * 32 + c4 * 2];
                v1 = src[row * 32 + c4 * 2 + 1];
            }
            ushort4 b0, b1;
            b0.x = f2bf(v0.x); b0.y = f2bf(v0.y); b0.z = f2bf(v0.z); b0.w = f2bf(v0.w);
            b1.x = f2bf(v1.x); b1.y = f2bf(v1.y); b1.z = f2bf(v1.z); b1.w = f2bf(v1.w);
            int chs = (c4 ^ (r & 7)) * 8;
            *(ushort4*)&As[r * FDIM + chs] = b0;
            *(ushort4*)&As[r * FDIM + chs + 4] = b1;
        }
    } else {
        const uint4* src = (const uint4*)Ain;  // 16 chunks per row
        for (int t = tid; t < 1024; t += 256) {
            int r = t >> 4, ch = t & 15;
            int row = row0 + r;
            uint4 v = make_uint4(0, 0, 0, 0);
            if (row < n) v = src[row * 16 + ch];
            *(uint4*)&As[r * FDIM + (ch ^ (r & 7)) * 8] = v;
        }
    }
    __syncthreads();

    int wave = tid >> 6, lane = tid & 63;
    int lr = lane & 15, lg = lane >> 4;
    f32x4 acc[8];
#pragma unroll
    for (int i = 0; i < 8; i++) acc[i] = (f32x4){0.f, 0.f, 0.f, 0.f};

#pragma unroll
    for (int k0 = 0; k0 < 4; k0++) {
        int kch = k0 * 4 + lg;   // 16B chunk index along k
        int ar = wave * 16 + lr;
        s16x8 a = *(const s16x8*)&As[ar * FDIM + (kch ^ (ar & 7)) * 8];
#pragma unroll
        for (int ct = 0; ct < 8; ct++) {
            int bc = ct * 16 + lr;
            s16x8 b = *(const s16x8*)&Bs[bc * FDIM + (kch ^ (bc & 7)) * 8];
            acc[ct] = __builtin_amdgcn_mfma_f32_16x16x32_bf16(a, b, acc[ct], 0, 0, 0);
        }
    }
    // epilogue: row = wave*16 + lg*4 + r, col = ct*16 + lr
#pragma unroll
    for (int ct = 0; ct < 8; ct++) {
        int col = ct * 16 + lr;
        float bv = bias ? bias[col] : 0.f;
#pragma unroll
        for (int r = 0; r < 4; r++) {
            int row = row0 + wave * 16 + lg * 4 + r;
            if (row < n) Cout[(size_t)row * FDIM + col] = f2bf(acc[ct][r] + bv);
        }
    }
}

// ------------- aggregate: h = relu(gather(hw)*w + hw*sn), bf16 in/out -------------
// csr is interleaved (src, w_bits). Neighbor loop unrolled x4 with batched
// independent gathers for memory-level parallelism.
__global__ __launch_bounds__(256) void k_aggregate(const ushort* __restrict__ hw,
                                                   const int* __restrict__ rowptr,
                                                   const int2* __restrict__ csr,
                                                   const float* __restrict__ dis,
                                                   ushort* __restrict__ h, int n) {
    int node = blockIdx.x * 8 + threadIdx.y;
    if (node >= n) return;
    int q = threadIdx.x;  // 0..31, features q*4..q*4+3
    const ushort4* hv = (const ushort4*)hw;
    float d = dis[node];
    float sn = d * d;
    ushort4 s4 = hv[node * 32 + q];
    float ax = bf2f(s4.x) * sn, ay = bf2f(s4.y) * sn, az = bf2f(s4.z) * sn, aw = bf2f(s4.w) * sn;
    int j = rowptr[node], end = rowptr[node + 1];
    for (; j + 4 <= end; j += 4) {
        int2 e0 = csr[j], e1 = csr[j + 1], e2 = csr[j + 2], e3 = csr[j + 3];
        ushort4 v0 = hv[e0.x * 32 + q];
        ushort4 v1 = hv[e1.x * 32 + q];
        ushort4 v2 = hv[e2.x * 32 + q];
        ushort4 v3 = hv[e3.x * 32 + q];
        float w0 = __int_as_float(e0.y), w1 = __int_as_float(e1.y);
        float w2 = __int_as_float(e2.y), w3 = __int_as_float(e3.y);
        ax += bf2f(v0.x) * w0; ay += bf2f(v0.y) * w0; az += bf2f(v0.z) * w0; aw += bf2f(v0.w) * w0;
        ax += bf2f(v1.x) * w1; ay += bf2f(v1.y) * w1; az += bf2f(v1.z) * w1; aw += bf2f(v1.w) * w1;
        ax += bf2f(v2.x) * w2; ay += bf2f(v2.y) * w2; az += bf2f(v2.z) * w2; aw += bf2f(v2.w) * w2;
        ax += bf2f(v3.x) * w3; ay += bf2f(v3.y) * w3; az += bf2f(v3.z) * w3; aw += bf2f(v3.w) * w3;
    }
    for (; j < end; j++) {
        int2 e = csr[j];
        ushort4 v = hv[e.x * 32 + q];
        float w = __int_as_float(e.y);
        ax += bf2f(v.x) * w; ay += bf2f(v.y) * w; az += bf2f(v.z) * w; aw += bf2f(v.w) * w;
    }
    ushort4 o;
    o.x = f2bf(fmaxf(ax, 0.f)); o.y = f2bf(fmaxf(ay, 0.f));
    o.z = f2bf(fmaxf(az, 0.f)); o.w = f2bf(fmaxf(aw, 0.f));
    ((ushort4*)h)[node * 32 + q] = o;
}

// ------- final: logits = h @ lt1_W + b via MFMA; out = log_softmax(logits) --------
// WTf is [48][128] bf16 (cols 40..47 zero).
__global__ __launch_bounds__(256) void k_final_mfma(const ushort* __restrict__ h,
                                                    const ushort* __restrict__ WTf,
                                                    const float* __restrict__ bias,
                                                    float* __restrict__ out, int n, int C) {
    __shared__ ushort As[64 * FDIM];   // 16 KB
    __shared__ ushort Bs[48 * FDIM];   // 12 KB
    int tid = threadIdx.x;
    int row0 = blockIdx.x * 64;

    // stage B: 48 rows x 16 chunks
    {
        const uint4* src = (const uint4*)WTf;
        for (int t = tid; t < 768; t += 256) {
            int r = t >> 4, ch = t & 15;
            uint4 v = src[t];
            *(uint4*)&Bs[r * FDIM + (ch ^ (r & 7)) * 8] = v;
        }
    }
    // stage A: 64 rows of h (bf16)
    {
        const uint4* src = (const uint4*)h;
        for (int t = tid; t < 1024; t += 256) {
            int r = t >> 4, ch = t & 15;
            int row = row0 + r;
            uint4 v = make_uint4(0, 0, 0, 0);
            if (row < n) v = src[row * 16 + ch];
            *(uint4*)&As[r * FDIM + (ch ^ (r & 7)) * 8] = v;
        }
    }
    __syncthreads();

    int wave = tid >> 6, lane = tid & 63;
    int lr = lane & 15, lg = lane >> 4;
    f32x4 acc[3];
#pragma unroll
    for (int i = 0; i < 3; i++) acc[i] = (f32x4){0.f, 0.f, 0.f, 0.f};

#pragma unroll
    for (int k0 = 0; k0 < 4; k0++) {
        int kch = k0 * 4 + lg;
        int ar = wave * 16 + lr;
        s16x8 a = *(const s16x8*)&As[ar * FDIM + (kch ^ (ar & 7)) * 8];
#pragma unroll
        for (int ct = 0; ct < 3; ct++) {
            int bc = ct * 16 + lr;
            s16x8 b = *(const s16x8*)&Bs[bc * FDIM + (kch ^ (bc & 7)) * 8];
            acc[ct] = __builtin_amdgcn_mfma_f32_16x16x32_bf16(a, b, acc[ct], 0, 0, 0);
        }
    }

    // bias per lane per column tile; invalid cols get 0 (masked below)
    float bv[3];
#pragma unroll
    for (int ct = 0; ct < 3; ct++) {
        int col = ct * 16 + lr;
        bv[ct] = (col < C) ? bias[col] : 0.f;
    }
    bool v2ok = (32 + lr) < C;  // ct==2 validity (cols 32..47)

    // per accumulator reg r: row = wave*16 + lg*4 + r; softmax over 48 cols (mask >=C)
#pragma unroll
    for (int r = 0; r < 4; r++) {
        float l0 = acc[0][r] + bv[0];
        float l1 = acc[1][r] + bv[1];
        float l2 = acc[2][r] + bv[2];
        float m = fmaxf(l0, l1);
        if (v2ok) m = fmaxf(m, l2);
#pragma unroll
        for (int off = 1; off < 16; off <<= 1) m = fmaxf(m, __shfl_xor(m, off));
        float e = __expf(l0 - m) + __expf(l1 - m) + (v2ok ? __expf(l2 - m) : 0.f);
#pragma unroll
        for (int off = 1; off < 16; off <<= 1) e += __shfl_xor(e, off);
        float lse = m + __logf(e);
        int row = row0 + wave * 16 + lg * 4 + r;
        if (row < n) {
            out[(size_t)row * C + lr] = l0 - lse;
            out[(size_t)row * C + 16 + lr] = l1 - lse;
            if (v2ok) out[(size_t)row * C + 32 + lr] = l2 - lse;
        }
    }
}

extern "C" void kernel_launch(void* const* d_in, const int* in_sizes, int n_in,
                              void* d_out, int out_size, void* d_ws, size_t ws_size,
                              hipStream_t stream) {
    const float* x      = (const float*)d_in[0];
    const int*   ei     = (const int*)d_in[1];
    const float* E_meta = (const float*)d_in[2];
    const float* w0     = (const float*)d_in[3];
    const float* b0     = (const float*)d_in[4];
    const float* gcn_W  = (const float*)d_in[5];
    const float* gcn_b  = (const float*)d_in[6];
    const float* lt1_W  = (const float*)d_in[7];
    const float* lt1_b  = (const float*)d_in[8];
    float* out = (float*)d_out;

    const int N = in_sizes[0] / FDIM;
    const int E = in_sizes[1] / 2;
    const int L = in_sizes[5] / (FDIM * FDIM);
    const int C = in_sizes[7] / FDIM;

    char* p = (char*)d_ws;
    auto alloc = [&](size_t bytes) {
        void* r = (void*)p;
        p += (bytes + 255) / 256 * 256;
        return r;
    };
    ushort* WT0    = (ushort*)alloc((size_t)FDIM * FDIM * 2);
    ushort* WTl    = (ushort*)alloc((size_t)L * FDIM * FDIM * 2);
    ushort* WTf    = (ushort*)alloc((size_t)48 * FDIM * 2);
    int*    counts = (int*)alloc((size_t)N * 4);
    int*    rowptr = (int*)alloc((size_t)(N + 1) * 4);
    float*  dis    = (float*)alloc((size_t)N * 4);
    int*    parts  = (int*)alloc(64 * 4);
    int2*   csr    = (int2*)alloc((size_t)E * 8);
    ushort* hA     = (ushort*)alloc((size_t)N * FDIM * 2);
    ushort* hB     = (ushort*)alloc((size_t)N * FDIM * 2);

    const int n4 = N / 4;                       // N divisible by 4 (50000)
    const int nb = (n4 + 255) / 256;            // scan blocks (1024 elems each)

    // weight prep
    k_new_w0t<<<FDIM, FDIM, 0, stream>>>(w0, E_meta, b0, WT0);
    k_transpose_w<<<L * FDIM, FDIM, 0, stream>>>(gcn_W, WTl);
    k_prep_wtf<<<48, FDIM, 0, stream>>>(lt1_W, WTf, C);

    // graph preprocessing
    k_zero<<<(N + 255) / 256, 256, 0, stream>>>(counts, N);
    k_count<<<(E + 255) / 256, 256, 0, stream>>>(ei, counts, E);
    k_blocksum<<<nb, 256, 0, stream>>>(counts, parts, n4);
    k_scanpart<<<1, 64, 0, stream>>>(parts, nb, rowptr, N, E);
    k_scanfinal<<<nb, 256, 0, stream>>>(counts, parts, rowptr, dis, n4);
    k_scatter<<<(E + 255) / 256, 256, 0, stream>>>(ei, rowptr, counts, dis, csr, E);

    int gemm_grid = (N + 63) / 64;
    // h0 = x @ new_w0  (fp32 A)
    k_gemm_mfma<1><<<gemm_grid, 256, 0, stream>>>(x, WT0, nullptr, hA, N);
    // GCN layers
    for (int l = 0; l < L; l++) {
        k_gemm_mfma<0><<<gemm_grid, 256, 0, stream>>>(hA, WTl + (size_t)l * FDIM * FDIM,
                                                      gcn_b + (size_t)l * FDIM, hB, N);
        dim3 ablk(32, 8);
        k_aggregate<<<(N + 7) / 8, ablk, 0, stream>>>(hB, rowptr, csr, dis, hA, N);
    }
    k_final_mfma<<<gemm_grid, 256, 0, stream>>>(hA, WTf, lt1_b, out, N, C);
}

// Round 5
// 267.562 us; speedup vs baseline: 2.1037x; 1.0601x over previous
//
#include <hip/hip_runtime.h>
#include <math.h>

#define FDIM 128

typedef short s16x8 __attribute__((ext_vector_type(8)));
typedef float f32x4 __attribute__((ext_vector_type(4)));

__device__ __forceinline__ ushort f2bf(float f) {
    union { float f; unsigned u; } v; v.f = f;
    unsigned u = v.u;
    unsigned r = (u + 0x7FFFu + ((u >> 16) & 1u)) >> 16;
    return (ushort)r;
}
__device__ __forceinline__ float bf2f(ushort b) {
    union { unsigned u; float f; } v; v.u = ((unsigned)b) << 16;
    return v.f;
}

// swizzled element index within a 128-elem row: chunk (k>>3) -> (k>>3)^(r&7)
__device__ __forceinline__ int swz_idx(int r, int k) {
    return (((k >> 3) ^ (r & 7)) << 3) | (k & 7);
}

// ---------------- WT0 pre-swizzled: row c holds relu(w0[k]*Em[c]+b0[k][c]) ----------
__global__ void k_new_w0t(const float* __restrict__ w0, const float* __restrict__ Em,
                          const float* __restrict__ b0, ushort* __restrict__ WT0) {
    int c = blockIdx.x, k = threadIdx.x;
    float v = w0[k] * Em[c] + b0[k * FDIM + c];
    WT0[c * FDIM + swz_idx(c, k)] = f2bf(v > 0.f ? v : 0.f);
}

// ---------------- WT[l] pre-swizzled: row c elem k = W[l][k][c] -----------------
__global__ void k_transpose_w(const float* __restrict__ W, ushort* __restrict__ WT) {
    int b = blockIdx.x;            // l*128 + c
    int l = b >> 7, c = b & 127;
    int k = threadIdx.x;
    WT[(size_t)l * FDIM * FDIM + c * FDIM + swz_idx(c, k)] =
        f2bf(W[(size_t)l * FDIM * FDIM + k * FDIM + c]);
}

// ---------------- WTf pre-swizzled [48][128]: row c elem k = lt1_W[k][c], pad 0 ------
__global__ void k_prep_wtf(const float* __restrict__ W, ushort* __restrict__ WTf, int C) {
    int c = blockIdx.x, k = threadIdx.x;
    WTf[c * FDIM + swz_idx(c, k)] = (c < C) ? f2bf(W[k * C + c]) : (ushort)0;
}

// ---------------- zero int buffer -----------------
__global__ void k_zero(int* __restrict__ p, int n) {
    int i = blockIdx.x * 256 + threadIdx.x;
    if (i < n) p[i] = 0;
}

// ---------------- per-dst degree count -----------------
__global__ void k_count(const int* __restrict__ ei, int* __restrict__ counts, int E) {
    int e = blockIdx.x * 256 + threadIdx.x;
    if (e < E) atomicAdd(&counts[ei[E + e]], 1);
}

// ---------------- scan phase 1: per-block (1024 elems) sums -----------------
__global__ __launch_bounds__(256) void k_blocksum(const int* __restrict__ counts,
                                                  int* __restrict__ partials, int n4) {
    int t = blockIdx.x * 256 + threadIdx.x;
    int4 c = (t < n4) ? ((const int4*)counts)[t] : make_int4(0, 0, 0, 0);
    int s = c.x + c.y + c.z + c.w;
    for (int off = 1; off < 64; off <<= 1) s += __shfl_xor(s, off);
    __shared__ int ws[4];
    if ((threadIdx.x & 63) == 0) ws[threadIdx.x >> 6] = s;
    __syncthreads();
    if (threadIdx.x == 0) partials[blockIdx.x] = ws[0] + ws[1] + ws[2] + ws[3];
}

// ---------------- scan phase 2: exclusive scan of <=64 partials (1 wave) ------------
__global__ void k_scanpart(int* __restrict__ partials, int nb,
                           int* __restrict__ rowptr, int N, int E) {
    int l = threadIdx.x;
    int v = (l < nb) ? partials[l] : 0;
    int s = v;
    for (int off = 1; off < 64; off <<= 1) {
        int t = __shfl_up(s, off);
        if (l >= off) s += t;
    }
    if (l < nb) partials[l] = s - v;
    if (l == 0) rowptr[N] = E;
}

// ---------------- scan phase 3: local scan + offset; write rowptr/dis, zero counts ----
__global__ __launch_bounds__(256) void k_scanfinal(int* __restrict__ counts,
                                                   const int* __restrict__ partials,
                                                   int* __restrict__ rowptr,
                                                   float* __restrict__ dis, int n4) {
    int tid = threadIdx.x;
    int t = blockIdx.x * 256 + tid;
    int4 c = (t < n4) ? ((const int4*)counts)[t] : make_int4(0, 0, 0, 0);
    int s = c.x + c.y + c.z + c.w;
    int lane = tid & 63, wave = tid >> 6;
    int incl = s;
    for (int off = 1; off < 64; off <<= 1) {
        int tv = __shfl_up(incl, off);
        if (lane >= off) incl += tv;
    }
    __shared__ int wt[4];
    if (lane == 63) wt[wave] = incl;
    __syncthreads();
    int base = partials[blockIdx.x];
    for (int w = 0; w < wave; w++) base += wt[w];
    int excl = base + incl - s;
    if (t < n4) {
        ((int4*)rowptr)[t] = make_int4(excl, excl + c.x, excl + c.x + c.y, excl + c.x + c.y + c.z);
        float4 dv;
        dv.x = rsqrtf((float)c.x + 1.f); dv.y = rsqrtf((float)c.y + 1.f);
        dv.z = rsqrtf((float)c.z + 1.f); dv.w = rsqrtf((float)c.w + 1.f);
        ((float4*)dis)[t] = dv;
        ((int4*)counts)[t] = make_int4(0, 0, 0, 0);
    }
}

// ---------------- scatter edges into CSR (by dst): ushort src only -----------------
__global__ void k_scatter(const int* __restrict__ ei, const int* __restrict__ rowptr,
                          int* __restrict__ cursor, ushort* __restrict__ csr_s, int E) {
    int e = blockIdx.x * 256 + threadIdx.x;
    if (e >= E) return;
    int s = ei[e], d = ei[E + e];
    int pos = atomicAdd(&cursor[d], 1);
    csr_s[rowptr[d] + pos] = (ushort)s;
}

// ------------- MFMA GEMM: C[n,128](bf16) = A[n,128] @ WT^T (+bias) ----------------
// WTs is PRE-SWIZZLED [128][128] bf16 (matches LDS layout exactly -> linear stage).
// A_FP32: fp32 A staged manually (bounds-checked); else bf16 A staged via
// global_load_lds with inverse-swizzled per-lane source (A must be row-padded!).
template <int A_FP32>
__global__ __launch_bounds__(256) void k_gemm_mfma(const void* __restrict__ Ain,
                                                   const ushort* __restrict__ WTs,
                                                   const float* __restrict__ bias,
                                                   ushort* __restrict__ Cout, int n) {
    __shared__ ushort As[64 * FDIM];    // 16 KB
    __shared__ ushort Bs[FDIM * FDIM];  // 32 KB
    int tid = threadIdx.x;
    int wave = tid >> 6, lane = tid & 63;
    int row0 = blockIdx.x * 64;

    // stage B: 2048 x 16B chunks, linear (source pre-swizzled)
    {
        const char* src = (const char*)WTs;
        char* dstb = (char*)Bs;
        int base = wave * 512;
#pragma unroll
        for (int i = 0; i < 8; i++) {
            int c0 = base + i * 64;
            __builtin_amdgcn_global_load_lds((const unsigned*)(src + (size_t)(c0 + lane) * 16),
                                             (unsigned*)(dstb + (size_t)c0 * 16), 16, 0, 0);
        }
    }
    // stage A
    if (A_FP32) {
        const float4* src = (const float4*)Ain;  // 32 float4 per row
        for (int t = tid; t < 1024; t += 256) {
            int r = t >> 4, c4 = t & 15;
            int row = row0 + r;
            float4 v0 = make_float4(0, 0, 0, 0), v1 = make_float4(0, 0, 0, 0);
            if (row < n) {
                v0 = src[row * 32 + c4 * 2];
                v1 = src[row * 32 + c4 * 2 + 1];
            }
            ushort4 b0, b1;
            b0.x = f2bf(v0.x); b0.y = f2bf(v0.y); b0.z = f2bf(v0.z); b0.w = f2bf(v0.w);
            b1.x = f2bf(v1.x); b1.y = f2bf(v1.y); b1.z = f2bf(v1.z); b1.w = f2bf(v1.w);
            int chs = (c4 ^ (r & 7)) * 8;
            *(ushort4*)&As[r * FDIM + chs] = b0;
            *(ushort4*)&As[r * FDIM + chs + 4] = b1;
        }
    } else {
        // bf16 A: per-lane inverse-swizzled global source, linear LDS dest
        const char* src = (const char*)Ain;
        char* dsta = (char*)As;
        int base = wave * 256;
#pragma unroll
        for (int i = 0; i < 4; i++) {
            int c0 = base + i * 64;
            int c = c0 + lane;
            int r = c >> 4, chp = c & 15;
            size_t goff = ((size_t)(row0 + r) * 16 + (chp ^ (r & 7))) * 16;
            __builtin_amdgcn_global_load_lds((const unsigned*)(src + goff),
                                             (unsigned*)(dsta + (size_t)c0 * 16), 16, 0, 0);
        }
    }
    __syncthreads();

    int lr = lane & 15, lg = lane >> 4;
    f32x4 acc[8];
#pragma unroll
    for (int i = 0; i < 8; i++) acc[i] = (f32x4){0.f, 0.f, 0.f, 0.f};

#pragma unroll
    for (int k0 = 0; k0 < 4; k0++) {
        int kch = k0 * 4 + lg;   // 16B chunk index along k
        int ar = wave * 16 + lr;
        s16x8 a = *(const s16x8*)&As[ar * FDIM + (kch ^ (ar & 7)) * 8];
#pragma unroll
        for (int ct = 0; ct < 8; ct++) {
            int bc = ct * 16 + lr;
            s16x8 b = *(const s16x8*)&Bs[bc * FDIM + (kch ^ (bc & 7)) * 8];
            acc[ct] = __builtin_amdgcn_mfma_f32_16x16x32_bf16(a, b, acc[ct], 0, 0, 0);
        }
    }
    // epilogue: row = wave*16 + lg*4 + r, col = ct*16 + lr
#pragma unroll
    for (int ct = 0; ct < 8; ct++) {
        int col = ct * 16 + lr;
        float bv = bias ? bias[col] : 0.f;
#pragma unroll
        for (int r = 0; r < 4; r++) {
            int row = row0 + wave * 16 + lg * 4 + r;
            if (row < n) Cout[(size_t)row * FDIM + col] = f2bf(acc[ct][r] + bv);
        }
    }
}

// ------------- aggregate: h = relu(d*(self*d + sum dis[s]*hw[s])), bf16 -------------
__global__ __launch_bounds__(256) void k_aggregate(const ushort* __restrict__ hw,
                                                   const int* __restrict__ rowptr,
                                                   const ushort* __restrict__ csr_s,
                                                   const float* __restrict__ dis,
                                                   ushort* __restrict__ h, int n) {
    int node = blockIdx.x * 8 + threadIdx.y;
    if (node >= n) return;
    int q = threadIdx.x;  // 0..31, features q*4..q*4+3
    const ushort4* hv = (const ushort4*)hw;
    float d = dis[node];
    ushort4 s4 = hv[node * 32 + q];
    float ax = bf2f(s4.x) * d, ay = bf2f(s4.y) * d, az = bf2f(s4.z) * d, aw = bf2f(s4.w) * d;
    int j = rowptr[node], end = rowptr[node + 1];
    for (; j + 4 <= end; j += 4) {
        int s0 = csr_s[j], s1 = csr_s[j + 1], s2 = csr_s[j + 2], s3 = csr_s[j + 3];
        float w0 = dis[s0], w1 = dis[s1], w2 = dis[s2], w3 = dis[s3];
        ushort4 v0 = hv[s0 * 32 + q];
        ushort4 v1 = hv[s1 * 32 + q];
        ushort4 v2 = hv[s2 * 32 + q];
        ushort4 v3 = hv[s3 * 32 + q];
        ax += bf2f(v0.x) * w0; ay += bf2f(v0.y) * w0; az += bf2f(v0.z) * w0; aw += bf2f(v0.w) * w0;
        ax += bf2f(v1.x) * w1; ay += bf2f(v1.y) * w1; az += bf2f(v1.z) * w1; aw += bf2f(v1.w) * w1;
        ax += bf2f(v2.x) * w2; ay += bf2f(v2.y) * w2; az += bf2f(v2.z) * w2; aw += bf2f(v2.w) * w2;
        ax += bf2f(v3.x) * w3; ay += bf2f(v3.y) * w3; az += bf2f(v3.z) * w3; aw += bf2f(v3.w) * w3;
    }
    for (; j < end; j++) {
        int s = csr_s[j];
        float w = dis[s];
        ushort4 v = hv[s * 32 + q];
        ax += bf2f(v.x) * w; ay += bf2f(v.y) * w; az += bf2f(v.z) * w; aw += bf2f(v.w) * w;
    }
    ushort4 o;
    o.x = f2bf(fmaxf(ax * d, 0.f)); o.y = f2bf(fmaxf(ay * d, 0.f));
    o.z = f2bf(fmaxf(az * d, 0.f)); o.w = f2bf(fmaxf(aw * d, 0.f));
    ((ushort4*)h)[node * 32 + q] = o;
}

// ------- final: logits = h @ lt1_W + b via MFMA; out = log_softmax(logits) --------
// WTf is PRE-SWIZZLED [48][128] bf16 (cols 40..47 zero). h must be row-padded.
__global__ __launch_bounds__(256) void k_final_mfma(const ushort* __restrict__ h,
                                                    const ushort* __restrict__ WTf,
                                                    const float* __restrict__ bias,
                                                    float* __restrict__ out, int n, int C) {
    __shared__ ushort As[64 * FDIM];   // 16 KB
    __shared__ ushort Bs[48 * FDIM];   // 12 KB
    int tid = threadIdx.x;
    int wave = tid >> 6, lane = tid & 63;
    int row0 = blockIdx.x * 64;

    // stage B: 768 chunks, linear
    {
        const char* src = (const char*)WTf;
        char* dstb = (char*)Bs;
        int base = wave * 192;
#pragma unroll
        for (int i = 0; i < 3; i++) {
            int c0 = base + i * 64;
            __builtin_amdgcn_global_load_lds((const unsigned*)(src + (size_t)(c0 + lane) * 16),
                                             (unsigned*)(dstb + (size_t)c0 * 16), 16, 0, 0);
        }
    }
    // stage A: 1024 chunks, inverse-swizzled source
    {
        const char* src = (const char*)h;
        char* dsta = (char*)As;
        int base = wave * 256;
#pragma unroll
        for (int i = 0; i < 4; i++) {
            int c0 = base + i * 64;
            int c = c0 + lane;
            int r = c >> 4, chp = c & 15;
            size_t goff = ((size_t)(row0 + r) * 16 + (chp ^ (r & 7))) * 16;
            __builtin_amdgcn_global_load_lds((const unsigned*)(src + goff),
                                             (unsigned*)(dsta + (size_t)c0 * 16), 16, 0, 0);
        }
    }
    __syncthreads();

    int lr = lane & 15, lg = lane >> 4;
    f32x4 acc[3];
#pragma unroll
    for (int i = 0; i < 3; i++) acc[i] = (f32x4){0.f, 0.f, 0.f, 0.f};

#pragma unroll
    for (int k0 = 0; k0 < 4; k0++) {
        int kch = k0 * 4 + lg;
        int ar = wave * 16 + lr;
        s16x8 a = *(const s16x8*)&As[ar * FDIM + (kch ^ (ar & 7)) * 8];
#pragma unroll
        for (int ct = 0; ct < 3; ct++) {
            int bc = ct * 16 + lr;
            s16x8 b = *(const s16x8*)&Bs[bc * FDIM + (kch ^ (bc & 7)) * 8];
            acc[ct] = __builtin_amdgcn_mfma_f32_16x16x32_bf16(a, b, acc[ct], 0, 0, 0);
        }
    }

    float bv[3];
#pragma unroll
    for (int ct = 0; ct < 3; ct++) {
        int col = ct * 16 + lr;
        bv[ct] = (col < C) ? bias[col] : 0.f;
    }
    bool v2ok = (32 + lr) < C;

#pragma unroll
    for (int r = 0; r < 4; r++) {
        float l0 = acc[0][r] + bv[0];
        float l1 = acc[1][r] + bv[1];
        float l2 = acc[2][r] + bv[2];
        float m = fmaxf(l0, l1);
        if (v2ok) m = fmaxf(m, l2);
#pragma unroll
        for (int off = 1; off < 16; off <<= 1) m = fmaxf(m, __shfl_xor(m, off));
        float e = __expf(l0 - m) + __expf(l1 - m) + (v2ok ? __expf(l2 - m) : 0.f);
#pragma unroll
        for (int off = 1; off < 16; off <<= 1) e += __shfl_xor(e, off);
        float lse = m + __logf(e);
        int row = row0 + wave * 16 + lg * 4 + r;
        if (row < n) {
            out[(size_t)row * C + lr] = l0 - lse;
            out[(size_t)row * C + 16 + lr] = l1 - lse;
            if (v2ok) out[(size_t)row * C + 32 + lr] = l2 - lse;
        }
    }
}

extern "C" void kernel_launch(void* const* d_in, const int* in_sizes, int n_in,
                              void* d_out, int out_size, void* d_ws, size_t ws_size,
                              hipStream_t stream) {
    const float* x      = (const float*)d_in[0];
    const int*   ei     = (const int*)d_in[1];
    const float* E_meta = (const float*)d_in[2];
    const float* w0     = (const float*)d_in[3];
    const float* b0     = (const float*)d_in[4];
    const float* gcn_W  = (const float*)d_in[5];
    const float* gcn_b  = (const float*)d_in[6];
    const float* lt1_W  = (const float*)d_in[7];
    const float* lt1_b  = (const float*)d_in[8];
    float* out = (float*)d_out;

    const int N = in_sizes[0] / FDIM;
    const int E = in_sizes[1] / 2;
    const int L = in_sizes[5] / (FDIM * FDIM);
    const int C = in_sizes[7] / FDIM;

    char* p = (char*)d_ws;
    auto alloc = [&](size_t bytes) {
        void* r = (void*)p;
        p += (bytes + 255) / 256 * 256;
        return r;
    };
    ushort* WT0    = (ushort*)alloc((size_t)FDIM * FDIM * 2);
    ushort* WTl    = (ushort*)alloc((size_t)L * FDIM * FDIM * 2);
    ushort* WTf    = (ushort*)alloc((size_t)48 * FDIM * 2);
    int*    counts = (int*)alloc((size_t)N * 4);
    int*    rowptr = (int*)alloc((size_t)(N + 1) * 4);
    float*  dis    = (float*)alloc((size_t)N * 4);
    int*    parts  = (int*)alloc(64 * 4);
    ushort* csr_s  = (ushort*)alloc((size_t)E * 2);
    // h buffers padded +128 rows: unmasked async A-staging of tail blocks
    ushort* hA     = (ushort*)alloc((size_t)(N + 128) * FDIM * 2);
    ushort* hB     = (ushort*)alloc((size_t)(N + 128) * FDIM * 2);

    const int n4 = N / 4;                       // N divisible by 4 (50000)
    const int nb = (n4 + 255) / 256;            // scan blocks (1024 elems each)

    // weight prep (pre-swizzled layouts)
    k_new_w0t<<<FDIM, FDIM, 0, stream>>>(w0, E_meta, b0, WT0);
    k_transpose_w<<<L * FDIM, FDIM, 0, stream>>>(gcn_W, WTl);
    k_prep_wtf<<<48, FDIM, 0, stream>>>(lt1_W, WTf, C);

    // graph preprocessing
    k_zero<<<(N + 255) / 256, 256, 0, stream>>>(counts, N);
    k_count<<<(E + 255) / 256, 256, 0, stream>>>(ei, counts, E);
    k_blocksum<<<nb, 256, 0, stream>>>(counts, parts, n4);
    k_scanpart<<<1, 64, 0, stream>>>(parts, nb, rowptr, N, E);
    k_scanfinal<<<nb, 256, 0, stream>>>(counts, parts, rowptr, dis, n4);
    k_scatter<<<(E + 255) / 256, 256, 0, stream>>>(ei, rowptr, counts, csr_s, E);

    int gemm_grid = (N + 63) / 64;
    // h0 = x @ new_w0  (fp32 A, bounds-checked staging)
    k_gemm_mfma<1><<<gemm_grid, 256, 0, stream>>>(x, WT0, nullptr, hA, N);
    // GCN layers
    for (int l = 0; l < L; l++) {
        k_gemm_mfma<0><<<gemm_grid, 256, 0, stream>>>(hA, WTl + (size_t)l * FDIM * FDIM,
                                                      gcn_b + (size_t)l * FDIM, hB, N);
        dim3 ablk(32, 8);
        k_aggregate<<<(N + 7) / 8, ablk, 0, stream>>>(hB, rowptr, csr_s, dis, hA, N);
    }
    k_final_mfma<<<gemm_grid, 256, 0, stream>>>(hA, WTf, lt1_b, out, N, C);
}

// Round 6
// 263.727 us; speedup vs baseline: 2.1343x; 1.0145x over previous
//
#include <hip/hip_runtime.h>
#include <math.h>

#define FDIM 128

typedef short s16x8 __attribute__((ext_vector_type(8)));
typedef float f32x4 __attribute__((ext_vector_type(4)));

__device__ __forceinline__ ushort f2bf(float f) {
    union { float f; unsigned u; } v; v.f = f;
    unsigned u = v.u;
    unsigned r = (u + 0x7FFFu + ((u >> 16) & 1u)) >> 16;
    return (ushort)r;
}
__device__ __forceinline__ float bf2f(ushort b) {
    union { unsigned u; float f; } v; v.u = ((unsigned)b) << 16;
    return v.f;
}

// swizzled element index within a 128-elem row: chunk (k>>3) -> (k>>3)^(r&7)
__device__ __forceinline__ int swz_idx(int r, int k) {
    return (((k >> 3) ^ (r & 7)) << 3) | (k & 7);
}

// ---------------- WT0 pre-swizzled: row c holds relu(w0[k]*Em[c]+b0[k][c]) ----------
__global__ void k_new_w0t(const float* __restrict__ w0, const float* __restrict__ Em,
                          const float* __restrict__ b0, ushort* __restrict__ WT0) {
    int c = blockIdx.x, k = threadIdx.x;
    float v = w0[k] * Em[c] + b0[k * FDIM + c];
    WT0[c * FDIM + swz_idx(c, k)] = f2bf(v > 0.f ? v : 0.f);
}

// ---------------- WT[l] pre-swizzled: row c elem k = W[l][k][c] -----------------
__global__ void k_transpose_w(const float* __restrict__ W, ushort* __restrict__ WT) {
    int b = blockIdx.x;            // l*128 + c
    int l = b >> 7, c = b & 127;
    int k = threadIdx.x;
    WT[(size_t)l * FDIM * FDIM + c * FDIM + swz_idx(c, k)] =
        f2bf(W[(size_t)l * FDIM * FDIM + k * FDIM + c]);
}

// ---------------- WTf pre-swizzled [48][128]: row c elem k = lt1_W[k][c], pad 0 ------
__global__ void k_prep_wtf(const float* __restrict__ W, ushort* __restrict__ WTf, int C) {
    int c = blockIdx.x, k = threadIdx.x;
    WTf[c * FDIM + swz_idx(c, k)] = (c < C) ? f2bf(W[k * C + c]) : (ushort)0;
}

// ---------------- zero int buffer -----------------
__global__ void k_zero(int* __restrict__ p, int n) {
    int i = blockIdx.x * 256 + threadIdx.x;
    if (i < n) p[i] = 0;
}

// ---------------- per-dst degree count -----------------
__global__ void k_count(const int* __restrict__ ei, int* __restrict__ counts, int E) {
    int e = blockIdx.x * 256 + threadIdx.x;
    if (e < E) atomicAdd(&counts[ei[E + e]], 1);
}

// ---------------- scan phase 1: per-block (1024 elems) sums -----------------
__global__ __launch_bounds__(256) void k_blocksum(const int* __restrict__ counts,
                                                  int* __restrict__ partials, int n4) {
    int t = blockIdx.x * 256 + threadIdx.x;
    int4 c = (t < n4) ? ((const int4*)counts)[t] : make_int4(0, 0, 0, 0);
    int s = c.x + c.y + c.z + c.w;
    for (int off = 1; off < 64; off <<= 1) s += __shfl_xor(s, off);
    __shared__ int ws[4];
    if ((threadIdx.x & 63) == 0) ws[threadIdx.x >> 6] = s;
    __syncthreads();
    if (threadIdx.x == 0) partials[blockIdx.x] = ws[0] + ws[1] + ws[2] + ws[3];
}

// ---------------- scan phase 2: exclusive scan of <=64 partials (1 wave) ------------
__global__ void k_scanpart(int* __restrict__ partials, int nb,
                           int* __restrict__ rowptr, int N, int E) {
    int l = threadIdx.x;
    int v = (l < nb) ? partials[l] : 0;
    int s = v;
    for (int off = 1; off < 64; off <<= 1) {
        int t = __shfl_up(s, off);
        if (l >= off) s += t;
    }
    if (l < nb) partials[l] = s - v;
    if (l == 0) rowptr[N] = E;
}

// ---------------- scan phase 3: local scan + offset; write rowptr/dis, zero counts ----
__global__ __launch_bounds__(256) void k_scanfinal(int* __restrict__ counts,
                                                   const int* __restrict__ partials,
                                                   int* __restrict__ rowptr,
                                                   float* __restrict__ dis, int n4) {
    int tid = threadIdx.x;
    int t = blockIdx.x * 256 + tid;
    int4 c = (t < n4) ? ((const int4*)counts)[t] : make_int4(0, 0, 0, 0);
    int s = c.x + c.y + c.z + c.w;
    int lane = tid & 63, wave = tid >> 6;
    int incl = s;
    for (int off = 1; off < 64; off <<= 1) {
        int tv = __shfl_up(incl, off);
        if (lane >= off) incl += tv;
    }
    __shared__ int wt[4];
    if (lane == 63) wt[wave] = incl;
    __syncthreads();
    int base = partials[blockIdx.x];
    for (int w = 0; w < wave; w++) base += wt[w];
    int excl = base + incl - s;
    if (t < n4) {
        ((int4*)rowptr)[t] = make_int4(excl, excl + c.x, excl + c.x + c.y, excl + c.x + c.y + c.z);
        float4 dv;
        dv.x = rsqrtf((float)c.x + 1.f); dv.y = rsqrtf((float)c.y + 1.f);
        dv.z = rsqrtf((float)c.z + 1.f); dv.w = rsqrtf((float)c.w + 1.f);
        ((float4*)dis)[t] = dv;
        ((int4*)counts)[t] = make_int4(0, 0, 0, 0);
    }
}

// ---------------- scatter edges into CSR (by dst): ushort src only -----------------
__global__ void k_scatter(const int* __restrict__ ei, const int* __restrict__ rowptr,
                          int* __restrict__ cursor, ushort* __restrict__ csr_s, int E) {
    int e = blockIdx.x * 256 + threadIdx.x;
    if (e >= E) return;
    int s = ei[e], d = ei[E + e];
    int pos = atomicAdd(&cursor[d], 1);
    csr_s[rowptr[d] + pos] = (ushort)s;
}

// ------------- MFMA GEMM: C[n,128](bf16) = scale ⊙ (A[n,128] @ WT^T + bias) ----------
// BM=128. WTs is PRE-SWIZZLED [128][128] bf16 (linear global_load_lds stage).
// A_FP32: fp32 A staged manually (bounds-checked); else bf16 A staged via
// global_load_lds with inverse-swizzled per-lane source (A must be row-padded).
// Rows >= n (up to block coverage) are stored as ZERO (gives the zero-row at n).
template <int A_FP32>
__global__ __launch_bounds__(256) void k_gemm_mfma(const void* __restrict__ Ain,
                                                   const ushort* __restrict__ WTs,
                                                   const float* __restrict__ bias,
                                                   const float* __restrict__ scale,
                                                   ushort* __restrict__ Cout, int n) {
    __shared__ ushort As[128 * FDIM];   // 32 KB
    __shared__ ushort Bs[FDIM * FDIM];  // 32 KB
    int tid = threadIdx.x;
    int wave = tid >> 6, lane = tid & 63;
    int row0 = blockIdx.x * 128;

    // stage B: 2048 x 16B chunks, linear (source pre-swizzled)
    {
        const char* src = (const char*)WTs;
        char* dstb = (char*)Bs;
        int base = wave * 512;
#pragma unroll
        for (int i = 0; i < 8; i++) {
            int c0 = base + i * 64;
            __builtin_amdgcn_global_load_lds((const unsigned*)(src + (size_t)(c0 + lane) * 16),
                                             (unsigned*)(dstb + (size_t)c0 * 16), 16, 0, 0);
        }
    }
    // stage A: 128 rows
    if (A_FP32) {
        const float4* src = (const float4*)Ain;  // 32 float4 per row
        for (int t = tid; t < 2048; t += 256) {
            int r = t >> 4, pr = t & 15;   // pr: float4-pair index = 16B bf16 chunk
            int row = row0 + r;
            float4 v0 = make_float4(0, 0, 0, 0), v1 = make_float4(0, 0, 0, 0);
            if (row < n) {
                v0 = src[row * 32 + pr * 2];
                v1 = src[row * 32 + pr * 2 + 1];
            }
            ushort4 b0, b1;
            b0.x = f2bf(v0.x); b0.y = f2bf(v0.y); b0.z = f2bf(v0.z); b0.w = f2bf(v0.w);
            b1.x = f2bf(v1.x); b1.y = f2bf(v1.y); b1.z = f2bf(v1.z); b1.w = f2bf(v1.w);
            int chs = (pr ^ (r & 7)) * 8;
            *(ushort4*)&As[r * FDIM + chs] = b0;
            *(ushort4*)&As[r * FDIM + chs + 4] = b1;
        }
    } else {
        // bf16 A: per-lane inverse-swizzled global source, linear LDS dest
        const char* src = (const char*)Ain;
        char* dsta = (char*)As;
        int base = wave * 512;
#pragma unroll
        for (int i = 0; i < 8; i++) {
            int c0 = base + i * 64;
            int c = c0 + lane;
            int r = c >> 4, chp = c & 15;
            size_t goff = ((size_t)(row0 + r) * 16 + (chp ^ (r & 7))) * 16;
            __builtin_amdgcn_global_load_lds((const unsigned*)(src + goff),
                                             (unsigned*)(dsta + (size_t)c0 * 16), 16, 0, 0);
        }
    }
    __syncthreads();

    int lr = lane & 15, lg = lane >> 4;
    f32x4 acc[2][8];
#pragma unroll
    for (int hf = 0; hf < 2; hf++)
#pragma unroll
        for (int i = 0; i < 8; i++) acc[hf][i] = (f32x4){0.f, 0.f, 0.f, 0.f};

#pragma unroll
    for (int k0 = 0; k0 < 4; k0++) {
        int kch = k0 * 4 + lg;   // 16B chunk index along k
        int ar0 = wave * 32 + lr;
        int ar1 = wave * 32 + 16 + lr;
        s16x8 a0 = *(const s16x8*)&As[ar0 * FDIM + (kch ^ (ar0 & 7)) * 8];
        s16x8 a1 = *(const s16x8*)&As[ar1 * FDIM + (kch ^ (ar1 & 7)) * 8];
#pragma unroll
        for (int ct = 0; ct < 8; ct++) {
            int bc = ct * 16 + lr;
            s16x8 b = *(const s16x8*)&Bs[bc * FDIM + (kch ^ (bc & 7)) * 8];
            acc[0][ct] = __builtin_amdgcn_mfma_f32_16x16x32_bf16(a0, b, acc[0][ct], 0, 0, 0);
            acc[1][ct] = __builtin_amdgcn_mfma_f32_16x16x32_bf16(a1, b, acc[1][ct], 0, 0, 0);
        }
    }
    // epilogue: row = row0 + wave*32 + hf*16 + lg*4 + r, col = ct*16 + lr
#pragma unroll
    for (int hf = 0; hf < 2; hf++) {
#pragma unroll
        for (int ct = 0; ct < 8; ct++) {
            int col = ct * 16 + lr;
            float bv = bias ? bias[col] : 0.f;
#pragma unroll
            for (int r = 0; r < 4; r++) {
                int row = row0 + wave * 32 + hf * 16 + lg * 4 + r;
                if (row < n) {
                    float sc = scale ? scale[row] : 1.f;
                    Cout[(size_t)row * FDIM + col] = f2bf((acc[hf][ct][r] + bv) * sc);
                } else {
                    Cout[(size_t)row * FDIM + col] = 0;  // zero row for aggregate clamp
                }
            }
        }
    }
}

// ------- aggregate: h[node] = relu(dis[node] * Σ_{s∈{node}∪N(node)} hws[s]) ---------
// hws rows are pre-scaled by dis (weights baked in). Row n is all-zero (clamp target).
__global__ __launch_bounds__(256) void k_aggregate(const ushort* __restrict__ hws,
                                                   const int* __restrict__ rowptr,
                                                   const ushort* __restrict__ csr_s,
                                                   const float* __restrict__ dis,
                                                   ushort* __restrict__ h, int n) {
    int node = blockIdx.x * 8 + threadIdx.y;
    if (node >= n) return;
    int q = threadIdx.x;  // 0..31, features q*4..q*4+3
    const ushort4* hv = (const ushort4*)hws;
    float d = dis[node];
    ushort4 s4 = hv[node * 32 + q];    // self (already scaled)
    float ax = bf2f(s4.x), ay = bf2f(s4.y), az = bf2f(s4.z), aw = bf2f(s4.w);
    int j = rowptr[node], end = rowptr[node + 1];
    for (; j < end; j += 8) {
        int idx[8];
#pragma unroll
        for (int b = 0; b < 8; b++) {
            int jj = j + b;
            idx[b] = (jj < end) ? (int)csr_s[jj] : n;   // clamp to zero row
        }
        ushort4 v[8];
#pragma unroll
        for (int b = 0; b < 8; b++) v[b] = hv[idx[b] * 32 + q];
#pragma unroll
        for (int b = 0; b < 8; b++) {
            ax += bf2f(v[b].x); ay += bf2f(v[b].y);
            az += bf2f(v[b].z); aw += bf2f(v[b].w);
        }
    }
    ushort4 o;
    o.x = f2bf(fmaxf(ax * d, 0.f)); o.y = f2bf(fmaxf(ay * d, 0.f));
    o.z = f2bf(fmaxf(az * d, 0.f)); o.w = f2bf(fmaxf(aw * d, 0.f));
    ((ushort4*)h)[node * 32 + q] = o;
}

// ------- final: logits = h @ lt1_W + b via MFMA; out = log_softmax(logits) --------
// WTf is PRE-SWIZZLED [48][128] bf16 (cols 40..47 zero). h must be row-padded.
__global__ __launch_bounds__(256) void k_final_mfma(const ushort* __restrict__ h,
                                                    const ushort* __restrict__ WTf,
                                                    const float* __restrict__ bias,
                                                    float* __restrict__ out, int n, int C) {
    __shared__ ushort As[64 * FDIM];   // 16 KB
    __shared__ ushort Bs[48 * FDIM];   // 12 KB
    int tid = threadIdx.x;
    int wave = tid >> 6, lane = tid & 63;
    int row0 = blockIdx.x * 64;

    // stage B: 768 chunks, linear
    {
        const char* src = (const char*)WTf;
        char* dstb = (char*)Bs;
        int base = wave * 192;
#pragma unroll
        for (int i = 0; i < 3; i++) {
            int c0 = base + i * 64;
            __builtin_amdgcn_global_load_lds((const unsigned*)(src + (size_t)(c0 + lane) * 16),
                                             (unsigned*)(dstb + (size_t)c0 * 16), 16, 0, 0);
        }
    }
    // stage A: 1024 chunks, inverse-swizzled source
    {
        const char* src = (const char*)h;
        char* dsta = (char*)As;
        int base = wave * 256;
#pragma unroll
        for (int i = 0; i < 4; i++) {
            int c0 = base + i * 64;
            int c = c0 + lane;
            int r = c >> 4, chp = c & 15;
            size_t goff = ((size_t)(row0 + r) * 16 + (chp ^ (r & 7))) * 16;
            __builtin_amdgcn_global_load_lds((const unsigned*)(src + goff),
                                             (unsigned*)(dsta + (size_t)c0 * 16), 16, 0, 0);
        }
    }
    __syncthreads();

    int lr = lane & 15, lg = lane >> 4;
    f32x4 acc[3];
#pragma unroll
    for (int i = 0; i < 3; i++) acc[i] = (f32x4){0.f, 0.f, 0.f, 0.f};

#pragma unroll
    for (int k0 = 0; k0 < 4; k0++) {
        int kch = k0 * 4 + lg;
        int ar = wave * 16 + lr;
        s16x8 a = *(const s16x8*)&As[ar * FDIM + (kch ^ (ar & 7)) * 8];
#pragma unroll
        for (int ct = 0; ct < 3; ct++) {
            int bc = ct * 16 + lr;
            s16x8 b = *(const s16x8*)&Bs[bc * FDIM + (kch ^ (bc & 7)) * 8];
            acc[ct] = __builtin_amdgcn_mfma_f32_16x16x32_bf16(a, b, acc[ct], 0, 0, 0);
        }
    }

    float bv[3];
#pragma unroll
    for (int ct = 0; ct < 3; ct++) {
        int col = ct * 16 + lr;
        bv[ct] = (col < C) ? bias[col] : 0.f;
    }
    bool v2ok = (32 + lr) < C;

#pragma unroll
    for (int r = 0; r < 4; r++) {
        float l0 = acc[0][r] + bv[0];
        float l1 = acc[1][r] + bv[1];
        float l2 = acc[2][r] + bv[2];
        float m = fmaxf(l0, l1);
        if (v2ok) m = fmaxf(m, l2);
#pragma unroll
        for (int off = 1; off < 16; off <<= 1) m = fmaxf(m, __shfl_xor(m, off));
        float e = __expf(l0 - m) + __expf(l1 - m) + (v2ok ? __expf(l2 - m) : 0.f);
#pragma unroll
        for (int off = 1; off < 16; off <<= 1) e += __shfl_xor(e, off);
        float lse = m + __logf(e);
        int row = row0 + wave * 16 + lg * 4 + r;
        if (row < n) {
            out[(size_t)row * C + lr] = l0 - lse;
            out[(size_t)row * C + 16 + lr] = l1 - lse;
            if (v2ok) out[(size_t)row * C + 32 + lr] = l2 - lse;
        }
    }
}

extern "C" void kernel_launch(void* const* d_in, const int* in_sizes, int n_in,
                              void* d_out, int out_size, void* d_ws, size_t ws_size,
                              hipStream_t stream) {
    const float* x      = (const float*)d_in[0];
    const int*   ei     = (const int*)d_in[1];
    const float* E_meta = (const float*)d_in[2];
    const float* w0     = (const float*)d_in[3];
    const float* b0     = (const float*)d_in[4];
    const float* gcn_W  = (const float*)d_in[5];
    const float* gcn_b  = (const float*)d_in[6];
    const float* lt1_W  = (const float*)d_in[7];
    const float* lt1_b  = (const float*)d_in[8];
    float* out = (float*)d_out;

    const int N = in_sizes[0] / FDIM;
    const int E = in_sizes[1] / 2;
    const int L = in_sizes[5] / (FDIM * FDIM);
    const int C = in_sizes[7] / FDIM;

    char* p = (char*)d_ws;
    auto alloc = [&](size_t bytes) {
        void* r = (void*)p;
        p += (bytes + 255) / 256 * 256;
        return r;
    };
    ushort* WT0    = (ushort*)alloc((size_t)FDIM * FDIM * 2);
    ushort* WTl    = (ushort*)alloc((size_t)L * FDIM * FDIM * 2);
    ushort* WTf    = (ushort*)alloc((size_t)48 * FDIM * 2);
    int*    counts = (int*)alloc((size_t)N * 4);
    int*    rowptr = (int*)alloc((size_t)(N + 1) * 4);
    float*  dis    = (float*)alloc((size_t)N * 4);
    int*    parts  = (int*)alloc(64 * 4);
    ushort* csr_s  = (ushort*)alloc((size_t)E * 2);
    // h buffers padded +256 rows: unmasked async A-staging of tail blocks (BM=128)
    ushort* hA     = (ushort*)alloc((size_t)(N + 256) * FDIM * 2);
    ushort* hB     = (ushort*)alloc((size_t)(N + 256) * FDIM * 2);

    const int n4 = N / 4;                       // N divisible by 4 (50000)
    const int nb = (n4 + 255) / 256;            // scan blocks (1024 elems each)

    // weight prep (pre-swizzled layouts)
    k_new_w0t<<<FDIM, FDIM, 0, stream>>>(w0, E_meta, b0, WT0);
    k_transpose_w<<<L * FDIM, FDIM, 0, stream>>>(gcn_W, WTl);
    k_prep_wtf<<<48, FDIM, 0, stream>>>(lt1_W, WTf, C);

    // graph preprocessing
    k_zero<<<(N + 255) / 256, 256, 0, stream>>>(counts, N);
    k_count<<<(E + 255) / 256, 256, 0, stream>>>(ei, counts, E);
    k_blocksum<<<nb, 256, 0, stream>>>(counts, parts, n4);
    k_scanpart<<<1, 64, 0, stream>>>(parts, nb, rowptr, N, E);
    k_scanfinal<<<nb, 256, 0, stream>>>(counts, parts, rowptr, dis, n4);
    k_scatter<<<(E + 255) / 256, 256, 0, stream>>>(ei, rowptr, counts, csr_s, E);

    int gemm_grid = (N + 127) / 128;
    // h0 = x @ new_w0  (fp32 A, bounds-checked staging; unscaled)
    k_gemm_mfma<1><<<gemm_grid, 256, 0, stream>>>(x, WT0, nullptr, nullptr, hA, N);
    // GCN layers: GEMM writes dis-scaled rows (+zero row at N); aggregate row-sums
    for (int l = 0; l < L; l++) {
        k_gemm_mfma<0><<<gemm_grid, 256, 0, stream>>>(hA, WTl + (size_t)l * FDIM * FDIM,
                                                      gcn_b + (size_t)l * FDIM, dis, hB, N);
        dim3 ablk(32, 8);
        k_aggregate<<<(N + 7) / 8, ablk, 0, stream>>>(hB, rowptr, csr_s, dis, hA, N);
    }
    k_final_mfma<<<(N + 63) / 64, 256, 0, stream>>>(hA, WTf, lt1_b, out, N, C);
}